// Round 3
// baseline (3473.150 us; speedup 1.0000x reference)
//
#include <hip/hip_runtime.h>

#define N_NODES 100000
#define N_EDGES 1600000
#define B_GRAPHS 64
#define BN_EPS 1e-5f

// ---------------- degree ----------------
__global__ void deg_kernel(const int* __restrict__ col, float* __restrict__ deg) {
    int t = blockIdx.x * blockDim.x + threadIdx.x;
    if (t < N_EDGES) atomicAdd(&deg[col[t]], 1.0f);
}

__global__ void dis_kernel(float* __restrict__ deg) {
    int i = blockIdx.x * blockDim.x + threadIdx.x;
    if (i < N_NODES) deg[i] = rsqrtf(deg[i] + 1.0f);  // +1 = self-loop
}

// ---------------- dense per-node matmul: xw[i][o] = sum_k h[i][k] * W[k][o] ----------------
template <int IN, int OUT>
__global__ void matmul_kernel(const float* __restrict__ h, const float* __restrict__ W,
                              float* __restrict__ xw) {
    __shared__ float Ws[IN * OUT];
    for (int k = threadIdx.x; k < IN * OUT; k += blockDim.x) Ws[k] = W[k];
    __syncthreads();
    int t = blockIdx.x * blockDim.x + threadIdx.x;
    const int total = N_NODES * OUT;
    if (t >= total) return;
    int i = t / OUT, o = t % OUT;
    float acc = 0.f;
#pragma unroll
    for (int k = 0; k < IN; k++) acc += h[i * IN + k] * Ws[k * OUT + o];
    xw[t] = acc;
}

// ---------------- edge aggregation: agg[col][f] += xw[row][f] * dis[row]*dis[col] ----------------
// one thread per (edge, 4-feature group): float4 gather, 4 scalar atomics
template <int F>
__global__ void agg_kernel(const int* __restrict__ row, const int* __restrict__ col,
                           const float* __restrict__ dis, const float* __restrict__ xw,
                           float* __restrict__ agg) {
    const int GPE = F / 4;  // float4 groups per edge
    long long t = (long long)blockIdx.x * blockDim.x + threadIdx.x;
    const long long total = (long long)N_EDGES * GPE;
    if (t >= total) return;
    int e = (int)(t / GPE);
    int g = (int)(t % GPE);
    int r = row[e], c = col[e];
    float nrm = dis[r] * dis[c];
    float4 v = ((const float4*)xw)[(long long)r * GPE + g];
    float* dst = &agg[(long long)c * F + g * 4];
    atomicAdd(dst + 0, v.x * nrm);
    atomicAdd(dst + 1, v.y * nrm);
    atomicAdd(dst + 2, v.z * nrm);
    atomicAdd(dst + 3, v.w * nrm);
}

// ---------------- self-loop + bias, and BN statistics ----------------
template <int F>
__global__ void post_stats_kernel(const float* __restrict__ xw, const float* __restrict__ dis,
                                  const float* __restrict__ b, float* __restrict__ agg,
                                  float* __restrict__ bn_sum, float* __restrict__ bn_sumsq) {
    __shared__ float s_sum[F];
    __shared__ float s_sq[F];
    if (threadIdx.x < F) { s_sum[threadIdx.x] = 0.f; s_sq[threadIdx.x] = 0.f; }
    __syncthreads();
    int t = blockIdx.x * blockDim.x + threadIdx.x;
    const int total = N_NODES * F;
    if (t < total) {
        int i = t / F, f = t % F;
        float d = dis[i];
        float v = agg[t] + xw[t] * d * d + b[f];
        agg[t] = v;
        atomicAdd(&s_sum[f], v);
        atomicAdd(&s_sq[f], v * v);
    }
    __syncthreads();
    if (threadIdx.x < F) {
        atomicAdd(&bn_sum[threadIdx.x], s_sum[threadIdx.x]);
        atomicAdd(&bn_sumsq[threadIdx.x], s_sq[threadIdx.x]);
    }
}

// ---------------- BN apply + ReLU ----------------
template <int F>
__global__ void bn_relu_kernel(const float* __restrict__ hpre, const float* __restrict__ bn_sum,
                               const float* __restrict__ bn_sumsq, const float* __restrict__ g,
                               const float* __restrict__ be, float* __restrict__ out) {
    int t = blockIdx.x * blockDim.x + threadIdx.x;
    const int total = N_NODES * F;
    if (t >= total) return;
    int f = t % F;
    const float invN = 1.0f / N_NODES;
    float mean = bn_sum[f] * invN;
    float var = bn_sumsq[f] * invN - mean * mean;
    float y = (hpre[t] - mean) * rsqrtf(var + BN_EPS) * g[f] + be[f];
    out[t] = y > 0.f ? y : 0.f;
}

// ---------------- mean pool: one wave per 256-node chunk, lane = feature ----------------
// batch is SORTED -> register-accumulate, flush one atomic per graph boundary.
#define POOL_CHUNK 256
__global__ void pool_kernel(const float* __restrict__ h, const int* __restrict__ batch,
                            float* __restrict__ pooled, float* __restrict__ cnt) {
    int lane = threadIdx.x;  // 0..63 = feature index (blockDim.x == 64)
    int start = blockIdx.x * POOL_CHUNK;
    int end = start + POOL_CHUNK;
    if (end > N_NODES) end = N_NODES;
    if (start >= end) return;
    int cur = batch[start];
    float acc = 0.f;
    float c = 0.f;
    for (int i = start; i < end; i++) {
        int b = batch[i];  // same address across lanes -> broadcast
        if (b != cur) {
            atomicAdd(&pooled[cur * 64 + lane], acc);
            if (lane == 0) atomicAdd(&cnt[cur], c);
            acc = 0.f; c = 0.f; cur = b;
        }
        acc += h[(long long)i * 64 + lane];
        c += 1.f;
    }
    atomicAdd(&pooled[cur * 64 + lane], acc);
    if (lane == 0) atomicAdd(&cnt[cur], c);
}

// ---------------- final linear ----------------
__global__ void final_kernel(const float* __restrict__ pooled, const float* __restrict__ cnt,
                             const float* __restrict__ fcW, const float* __restrict__ fcb,
                             float* __restrict__ out) {
    int t = blockIdx.x * blockDim.x + threadIdx.x;
    if (t >= B_GRAPHS * 10) return;
    int b = t / 10, j = t % 10;
    float inv = 1.0f / fmaxf(cnt[b], 1.0f);
    float acc = fcb[j];
#pragma unroll
    for (int f = 0; f < 64; f++) acc += pooled[b * 64 + f] * inv * fcW[f * 10 + j];
    out[t] = acc;
}

static inline int cdiv(long long a, int b) { return (int)((a + b - 1) / b); }

extern "C" void kernel_launch(void* const* d_in, const int* in_sizes, int n_in,
                              void* d_out, int out_size, void* d_ws, size_t ws_size,
                              hipStream_t stream) {
    const float* x  = (const float*)d_in[0];
    const int* ei   = (const int*)d_in[1];      // [2, E] int32
    const int* batch= (const int*)d_in[2];
    const float* W1 = (const float*)d_in[3];  const float* b1 = (const float*)d_in[4];
    const float* g1 = (const float*)d_in[5];  const float* be1= (const float*)d_in[6];
    const float* W2 = (const float*)d_in[7];  const float* b2 = (const float*)d_in[8];
    const float* g2 = (const float*)d_in[9];  const float* be2= (const float*)d_in[10];
    const float* W3 = (const float*)d_in[11]; const float* b3 = (const float*)d_in[12];
    const float* g3 = (const float*)d_in[13]; const float* be3= (const float*)d_in[14];
    const float* fcW= (const float*)d_in[15]; const float* fcb= (const float*)d_in[16];
    float* out = (float*)d_out;

    const int* row = ei;
    const int* col = ei + N_EDGES;

    // workspace layout (floats)
    float* ws = (float*)d_ws;
    float* dis    = ws;                          // N
    float* P1     = ws + 100000;                 // N*64
    float* P2     = P1 + N_NODES * 64;           // N*64
    float* P3     = P2 + N_NODES * 64;           // N*64
    float* bn_sum = P3 + N_NODES * 64;           // 64
    float* bn_sq  = bn_sum + 64;                 // 64
    float* pooled = bn_sq + 64;                  // 64*64
    float* cnt    = pooled + 64 * 64;            // 64

    const int BS = 256;

    // degree -> dis
    hipMemsetAsync(dis, 0, N_NODES * sizeof(float), stream);
    deg_kernel<<<cdiv(N_EDGES, BS), BS, 0, stream>>>(col, dis);
    dis_kernel<<<cdiv(N_NODES, BS), BS, 0, stream>>>(dis);

    // ---- layer 1: x(3) -> 16.  xw=P1, agg=P2, h1=P3
    matmul_kernel<3, 16><<<cdiv((long long)N_NODES * 16, BS), BS, 0, stream>>>(x, W1, P1);
    hipMemsetAsync(P2, 0, (size_t)N_NODES * 16 * sizeof(float), stream);
    agg_kernel<16><<<cdiv((long long)N_EDGES * 4, BS), BS, 0, stream>>>(row, col, dis, P1, P2);
    hipMemsetAsync(bn_sum, 0, 128 * sizeof(float), stream);
    post_stats_kernel<16><<<cdiv((long long)N_NODES * 16, BS), BS, 0, stream>>>(P1, dis, b1, P2, bn_sum, bn_sq);
    bn_relu_kernel<16><<<cdiv((long long)N_NODES * 16, BS), BS, 0, stream>>>(P2, bn_sum, bn_sq, g1, be1, P3);

    // ---- layer 2: h1(16) -> 32.  xw=P1, agg=P2, h2=P1 (xw dead at bn time)
    matmul_kernel<16, 32><<<cdiv((long long)N_NODES * 32, BS), BS, 0, stream>>>(P3, W2, P1);
    hipMemsetAsync(P2, 0, (size_t)N_NODES * 32 * sizeof(float), stream);
    agg_kernel<32><<<cdiv((long long)N_EDGES * 8, BS), BS, 0, stream>>>(row, col, dis, P1, P2);
    hipMemsetAsync(bn_sum, 0, 128 * sizeof(float), stream);
    post_stats_kernel<32><<<cdiv((long long)N_NODES * 32, BS), BS, 0, stream>>>(P1, dis, b2, P2, bn_sum, bn_sq);
    bn_relu_kernel<32><<<cdiv((long long)N_NODES * 32, BS), BS, 0, stream>>>(P2, bn_sum, bn_sq, g2, be2, P1);

    // ---- layer 3: h2(32) -> 64.  xw=P3, agg=P2, h3=P1
    matmul_kernel<32, 64><<<cdiv((long long)N_NODES * 64, BS), BS, 0, stream>>>(P1, W3, P3);
    hipMemsetAsync(P2, 0, (size_t)N_NODES * 64 * sizeof(float), stream);
    agg_kernel<64><<<cdiv((long long)N_EDGES * 16, BS), BS, 0, stream>>>(row, col, dis, P3, P2);
    hipMemsetAsync(bn_sum, 0, 128 * sizeof(float), stream);
    post_stats_kernel<64><<<cdiv((long long)N_NODES * 64, BS), BS, 0, stream>>>(P3, dis, b3, P2, bn_sum, bn_sq);
    bn_relu_kernel<64><<<cdiv((long long)N_NODES * 64, BS), BS, 0, stream>>>(P2, bn_sum, bn_sq, g3, be3, P1);

    // ---- pool + fc
    hipMemsetAsync(pooled, 0, (64 * 64 + 64) * sizeof(float), stream);
    pool_kernel<<<cdiv(N_NODES, POOL_CHUNK), 64, 0, stream>>>(P1, batch, pooled, cnt);
    final_kernel<<<1, B_GRAPHS * 10, 0, stream>>>(pooled, cnt, fcW, fcb, out);
}

// Round 4
// 1377.463 us; speedup vs baseline: 2.5214x; 2.5214x over previous
//
#include <hip/hip_runtime.h>

#define N_NODES 100000
#define N_EDGES 1600000
#define B_GRAPHS 64
#define BN_EPS 1e-5f
#define NBLK 391  // cdiv(N_NODES, 256)

static inline int cdiv(long long a, int b) { return (int)((a + b - 1) / b); }

// ---------------- degree histogram (int) ----------------
__global__ void deg_kernel(const int* __restrict__ col, int* __restrict__ deg) {
    int t = blockIdx.x * blockDim.x + threadIdx.x;
    if (t < N_EDGES) atomicAdd(&deg[col[t]], 1);
}

__global__ void dis_kernel(const int* __restrict__ deg, float* __restrict__ dis) {
    int i = blockIdx.x * blockDim.x + threadIdx.x;
    if (i < N_NODES) dis[i] = rsqrtf((float)deg[i] + 1.0f);  // +1 = self-loop
}

// ---------------- CSR build: two-level exclusive scan of deg ----------------
__global__ void blocksum_kernel(const int* __restrict__ deg, int* __restrict__ bsum) {
    __shared__ int s[256];
    int i = blockIdx.x * 256 + threadIdx.x;
    s[threadIdx.x] = (i < N_NODES) ? deg[i] : 0;
    __syncthreads();
    for (int off = 128; off > 0; off >>= 1) {
        if (threadIdx.x < off) s[threadIdx.x] += s[threadIdx.x + off];
        __syncthreads();
    }
    if (threadIdx.x == 0) bsum[blockIdx.x] = s[0];
}

__global__ void scanbsum_kernel(const int* __restrict__ bsum, int* __restrict__ boff) {
    __shared__ int s[512];
    int t = threadIdx.x;
    int v0 = (t < NBLK) ? bsum[t] : 0;
    s[t] = v0;
    __syncthreads();
    for (int off = 1; off < 512; off <<= 1) {
        int v = (t >= off) ? s[t - off] : 0;
        __syncthreads();
        s[t] += v;
        __syncthreads();
    }
    if (t < NBLK) boff[t] = s[t] - v0;  // exclusive
}

__global__ void writeptr_kernel(const int* __restrict__ deg, const int* __restrict__ boff,
                                int* __restrict__ row_ptr, int* __restrict__ pos) {
    __shared__ int s[256];
    int i = blockIdx.x * 256 + threadIdx.x;
    int d = (i < N_NODES) ? deg[i] : 0;
    s[threadIdx.x] = d;
    __syncthreads();
    for (int off = 1; off < 256; off <<= 1) {
        int v = (threadIdx.x >= off) ? s[threadIdx.x - off] : 0;
        __syncthreads();
        s[threadIdx.x] += v;
        __syncthreads();
    }
    if (i < N_NODES) {
        int p = boff[blockIdx.x] + s[threadIdx.x] - d;  // exclusive
        row_ptr[i] = p;
        pos[i] = p;
    }
}

__global__ void scatter_kernel(const int* __restrict__ row, const int* __restrict__ col,
                               int* __restrict__ pos, int* __restrict__ sorted_row) {
    int t = blockIdx.x * blockDim.x + threadIdx.x;
    if (t < N_EDGES) {
        int c = col[t];
        int p = atomicAdd(&pos[c], 1);
        sorted_row[p] = row[t];
    }
}

// ---------------- matmul + pre-scale by dis[i]: xw_s[i][o] = dis[i] * sum_k h[i][k]*W[k][o] ----------------
template <int IN, int OUT>
__global__ void matmul_scale_kernel(const float* __restrict__ h, const float* __restrict__ W,
                                    const float* __restrict__ dis, float* __restrict__ xw) {
    __shared__ float Ws[IN * OUT];
    for (int k = threadIdx.x; k < IN * OUT; k += blockDim.x) Ws[k] = W[k];
    __syncthreads();
    int t = blockIdx.x * blockDim.x + threadIdx.x;
    const int total = N_NODES * OUT;
    if (t >= total) return;
    int i = t / OUT, o = t % OUT;
    float acc = 0.f;
#pragma unroll
    for (int k = 0; k < IN; k++) acc += h[i * IN + k] * Ws[k * OUT + o];
    xw[t] = acc * dis[i];
}

// ---------------- CSR gather + self-loop + bias + BN stats ----------------
// agg[c][f] = dis[c] * (sum_{r in in(c)} xw_s[r][f] + xw_s[c][f]) + b[f]
template <int F>
__global__ void gather_stats_kernel(const int* __restrict__ row_ptr, const int* __restrict__ deg,
                                    const int* __restrict__ sorted_row, const float* __restrict__ dis,
                                    const float* __restrict__ xw, const float* __restrict__ b,
                                    float* __restrict__ agg, float* __restrict__ bn_sum,
                                    float* __restrict__ bn_sumsq) {
    __shared__ float s_sum[F];
    __shared__ float s_sq[F];
    if (threadIdx.x < F) { s_sum[threadIdx.x] = 0.f; s_sq[threadIdx.x] = 0.f; }
    __syncthreads();
    const int NPW = 64 / F;  // nodes per wave
    int gtid = blockIdx.x * blockDim.x + threadIdx.x;
    int lane = threadIdx.x & 63;
    int n = (gtid >> 6) * NPW + lane / F;
    int f = lane % F;
    if (n < N_NODES) {
        int start = row_ptr[n];
        int d = deg[n];
        float acc = xw[(long long)n * F + f];  // self-loop term
        for (int j = 0; j < d; j++) {
            int r = sorted_row[start + j];
            acc += xw[(long long)r * F + f];
        }
        float v = dis[n] * acc + b[f];
        agg[(long long)n * F + f] = v;
        atomicAdd(&s_sum[f], v);
        atomicAdd(&s_sq[f], v * v);
    }
    __syncthreads();
    if (threadIdx.x < F) {
        atomicAdd(&bn_sum[threadIdx.x], s_sum[threadIdx.x]);
        atomicAdd(&bn_sumsq[threadIdx.x], s_sq[threadIdx.x]);
    }
}

// ---------------- BN apply + ReLU ----------------
template <int F>
__global__ void bn_relu_kernel(const float* __restrict__ hpre, const float* __restrict__ bn_sum,
                               const float* __restrict__ bn_sumsq, const float* __restrict__ g,
                               const float* __restrict__ be, float* __restrict__ out) {
    int t = blockIdx.x * blockDim.x + threadIdx.x;
    const int total = N_NODES * F;
    if (t >= total) return;
    int f = t % F;
    const float invN = 1.0f / N_NODES;
    float mean = bn_sum[f] * invN;
    float var = bn_sumsq[f] * invN - mean * mean;
    float y = (hpre[t] - mean) * rsqrtf(var + BN_EPS) * g[f] + be[f];
    out[t] = y > 0.f ? y : 0.f;
}

// ---------------- mean pool: one wave per 256-node chunk, lane = feature ----------------
#define POOL_CHUNK 256
__global__ void pool_kernel(const float* __restrict__ h, const int* __restrict__ batch,
                            float* __restrict__ pooled, float* __restrict__ cnt) {
    int lane = threadIdx.x;  // 0..63 (blockDim.x == 64)
    int start = blockIdx.x * POOL_CHUNK;
    int end = start + POOL_CHUNK;
    if (end > N_NODES) end = N_NODES;
    if (start >= end) return;
    int cur = batch[start];
    float acc = 0.f;
    float c = 0.f;
    for (int i = start; i < end; i++) {
        int b = batch[i];  // broadcast
        if (b != cur) {
            atomicAdd(&pooled[cur * 64 + lane], acc);
            if (lane == 0) atomicAdd(&cnt[cur], c);
            acc = 0.f; c = 0.f; cur = b;
        }
        acc += h[(long long)i * 64 + lane];
        c += 1.f;
    }
    atomicAdd(&pooled[cur * 64 + lane], acc);
    if (lane == 0) atomicAdd(&cnt[cur], c);
}

// ---------------- final linear ----------------
__global__ void final_kernel(const float* __restrict__ pooled, const float* __restrict__ cnt,
                             const float* __restrict__ fcW, const float* __restrict__ fcb,
                             float* __restrict__ out) {
    int t = blockIdx.x * blockDim.x + threadIdx.x;
    if (t >= B_GRAPHS * 10) return;
    int b = t / 10, j = t % 10;
    float inv = 1.0f / fmaxf(cnt[b], 1.0f);
    float acc = fcb[j];
#pragma unroll
    for (int f = 0; f < 64; f++) acc += pooled[b * 64 + f] * inv * fcW[f * 10 + j];
    out[t] = acc;
}

extern "C" void kernel_launch(void* const* d_in, const int* in_sizes, int n_in,
                              void* d_out, int out_size, void* d_ws, size_t ws_size,
                              hipStream_t stream) {
    const float* x  = (const float*)d_in[0];
    const int* ei   = (const int*)d_in[1];
    const int* batch= (const int*)d_in[2];
    const float* W1 = (const float*)d_in[3];  const float* b1 = (const float*)d_in[4];
    const float* g1 = (const float*)d_in[5];  const float* be1= (const float*)d_in[6];
    const float* W2 = (const float*)d_in[7];  const float* b2 = (const float*)d_in[8];
    const float* g2 = (const float*)d_in[9];  const float* be2= (const float*)d_in[10];
    const float* W3 = (const float*)d_in[11]; const float* b3 = (const float*)d_in[12];
    const float* g3 = (const float*)d_in[13]; const float* be3= (const float*)d_in[14];
    const float* fcW= (const float*)d_in[15]; const float* fcb= (const float*)d_in[16];
    float* out = (float*)d_out;

    const int* row = ei;
    const int* col = ei + N_EDGES;

    // workspace layout
    char* wp = (char*)d_ws;
    float* dis       = (float*)wp;               wp += N_NODES * 4;
    int*   deg_i     = (int*)wp;                 wp += N_NODES * 4;
    int*   row_ptr   = (int*)wp;                 wp += N_NODES * 4;
    int*   pos       = (int*)wp;                 wp += N_NODES * 4;
    int*   bsum      = (int*)wp;                 wp += 512 * 4;
    int*   boff      = (int*)wp;                 wp += 512 * 4;
    int*   sorted_row= (int*)wp;                 wp += (size_t)N_EDGES * 4;
    float* bn_sum    = (float*)wp;               wp += 64 * 4;
    float* bn_sq     = (float*)wp;               wp += 64 * 4;
    float* pooled    = (float*)wp;               wp += 64 * 64 * 4;
    float* cnt       = (float*)wp;               wp += 64 * 4;
    float* X         = (float*)wp;               wp += (size_t)N_NODES * 64 * 4;
    float* Y         = (float*)wp;               wp += (size_t)N_NODES * 64 * 4;

    const int BS = 256;

    // ---- degree + dis + CSR build
    hipMemsetAsync(deg_i, 0, N_NODES * sizeof(int), stream);
    deg_kernel<<<cdiv(N_EDGES, BS), BS, 0, stream>>>(col, deg_i);
    dis_kernel<<<cdiv(N_NODES, BS), BS, 0, stream>>>(deg_i, dis);
    blocksum_kernel<<<NBLK, 256, 0, stream>>>(deg_i, bsum);
    scanbsum_kernel<<<1, 512, 0, stream>>>(bsum, boff);
    writeptr_kernel<<<NBLK, 256, 0, stream>>>(deg_i, boff, row_ptr, pos);
    scatter_kernel<<<cdiv(N_EDGES, BS), BS, 0, stream>>>(row, col, pos, sorted_row);

    // ---- layer 1: x(3) -> 16.  xw_s=X, agg=Y, h1=X
    matmul_scale_kernel<3, 16><<<cdiv((long long)N_NODES * 16, BS), BS, 0, stream>>>(x, W1, dis, X);
    hipMemsetAsync(bn_sum, 0, 128 * sizeof(float), stream);
    gather_stats_kernel<16><<<cdiv((long long)cdiv(N_NODES, 4) * 64, BS), BS, 0, stream>>>(
        row_ptr, deg_i, sorted_row, dis, X, b1, Y, bn_sum, bn_sq);
    bn_relu_kernel<16><<<cdiv((long long)N_NODES * 16, BS), BS, 0, stream>>>(Y, bn_sum, bn_sq, g1, be1, X);

    // ---- layer 2: h1(16, X) -> 32.  xw_s=Y, agg=X, h2=Y
    matmul_scale_kernel<16, 32><<<cdiv((long long)N_NODES * 32, BS), BS, 0, stream>>>(X, W2, dis, Y);
    hipMemsetAsync(bn_sum, 0, 128 * sizeof(float), stream);
    gather_stats_kernel<32><<<cdiv((long long)cdiv(N_NODES, 2) * 64, BS), BS, 0, stream>>>(
        row_ptr, deg_i, sorted_row, dis, Y, b2, X, bn_sum, bn_sq);
    bn_relu_kernel<32><<<cdiv((long long)N_NODES * 32, BS), BS, 0, stream>>>(X, bn_sum, bn_sq, g2, be2, Y);

    // ---- layer 3: h2(32, Y) -> 64.  xw_s=X, agg=Y, h3=X
    matmul_scale_kernel<32, 64><<<cdiv((long long)N_NODES * 64, BS), BS, 0, stream>>>(Y, W3, dis, X);
    hipMemsetAsync(bn_sum, 0, 128 * sizeof(float), stream);
    gather_stats_kernel<64><<<cdiv((long long)N_NODES * 64, BS), BS, 0, stream>>>(
        row_ptr, deg_i, sorted_row, dis, X, b3, Y, bn_sum, bn_sq);
    bn_relu_kernel<64><<<cdiv((long long)N_NODES * 64, BS), BS, 0, stream>>>(Y, bn_sum, bn_sq, g3, be3, X);

    // ---- pool + fc
    hipMemsetAsync(pooled, 0, (64 * 64 + 64) * sizeof(float), stream);
    pool_kernel<<<cdiv(N_NODES, POOL_CHUNK), 64, 0, stream>>>(X, batch, pooled, cnt);
    final_kernel<<<1, B_GRAPHS * 10, 0, stream>>>(pooled, cnt, fcW, fcb, out);
}

// Round 6
// 678.624 us; speedup vs baseline: 5.1179x; 2.0298x over previous
//
#include <hip/hip_runtime.h>

#define N_NODES 100000
#define N_EDGES 1600000
#define B_GRAPHS 64
#define BN_EPS 1e-5
#define NBLK 391      // cdiv(N_NODES, 256)
#define NB_STATS 1024 // blocks for matmul+stats kernels

static inline int cdiv(long long a, int b) { return (int)((a + b - 1) / b); }

// ---------------- degree histogram (int) ----------------
__global__ void deg_kernel(const int* __restrict__ col, int* __restrict__ deg) {
    int t = blockIdx.x * blockDim.x + threadIdx.x;
    if (t < N_EDGES) atomicAdd(&deg[col[t]], 1);
}

__global__ void dis_kernel(const int* __restrict__ deg, float* __restrict__ dis) {
    int i = blockIdx.x * blockDim.x + threadIdx.x;
    if (i < N_NODES) dis[i] = rsqrtf((float)deg[i] + 1.0f);  // +1 = self-loop
}

// ---------------- CSR build: two-level exclusive scan of deg ----------------
__global__ void blocksum_kernel(const int* __restrict__ deg, int* __restrict__ bsum) {
    __shared__ int s[256];
    int i = blockIdx.x * 256 + threadIdx.x;
    s[threadIdx.x] = (i < N_NODES) ? deg[i] : 0;
    __syncthreads();
    for (int off = 128; off > 0; off >>= 1) {
        if (threadIdx.x < off) s[threadIdx.x] += s[threadIdx.x + off];
        __syncthreads();
    }
    if (threadIdx.x == 0) bsum[blockIdx.x] = s[0];
}

__global__ void scanbsum_kernel(const int* __restrict__ bsum, int* __restrict__ boff) {
    __shared__ int s[512];
    int t = threadIdx.x;
    int v0 = (t < NBLK) ? bsum[t] : 0;
    s[t] = v0;
    __syncthreads();
    for (int off = 1; off < 512; off <<= 1) {
        int v = (t >= off) ? s[t - off] : 0;
        __syncthreads();
        s[t] += v;
        __syncthreads();
    }
    if (t < NBLK) boff[t] = s[t] - v0;  // exclusive
}

__global__ void writeptr_kernel(const int* __restrict__ deg, const int* __restrict__ boff,
                                int* __restrict__ row_ptr, int* __restrict__ pos) {
    __shared__ int s[256];
    int i = blockIdx.x * 256 + threadIdx.x;
    int d = (i < N_NODES) ? deg[i] : 0;
    s[threadIdx.x] = d;
    __syncthreads();
    for (int off = 1; off < 256; off <<= 1) {
        int v = (threadIdx.x >= off) ? s[threadIdx.x - off] : 0;
        __syncthreads();
        s[threadIdx.x] += v;
        __syncthreads();
    }
    if (i < N_NODES) {
        int p = boff[blockIdx.x] + s[threadIdx.x] - d;  // exclusive
        row_ptr[i] = p;
        pos[i] = p;
    }
}

__global__ void scatter_kernel(const int* __restrict__ row, const int* __restrict__ col,
                               int* __restrict__ pos, int* __restrict__ sorted_row) {
    int t = blockIdx.x * blockDim.x + threadIdx.x;
    if (t < N_EDGES) {
        int c = col[t];
        int p = atomicAdd(&pos[c], 1);
        sorted_row[p] = row[t];
    }
}

// ---------------- pre-scale x by dis, pad 3 -> 4 ----------------
__global__ void scale_x_kernel(const float* __restrict__ x, const float* __restrict__ dis,
                               float* __restrict__ xs4) {
    int i = blockIdx.x * blockDim.x + threadIdx.x;
    if (i < N_NODES) {
        float d = dis[i];
        xs4[i * 4 + 0] = x[i * 3 + 0] * d;
        xs4[i * 4 + 1] = x[i * 3 + 1] * d;
        xs4[i * 4 + 2] = x[i * 3 + 2] * d;
        xs4[i * 4 + 3] = 0.f;
    }
}

// ---------------- CSR gather at width F: agg[n] = dis[n] * (sum_{r in in(n)} hs[r] + hs[n]) ----------------
// hs pre-scaled by dis at source. One wave = 64/F nodes; lane = node_sub*F + f. Edge loop unrolled x4.
template <int F>
__global__ void gather_kernel(const int* __restrict__ row_ptr, const int* __restrict__ deg,
                              const int* __restrict__ sorted_row, const float* __restrict__ dis,
                              const float* __restrict__ hs, float* __restrict__ agg) {
    const int NPW = 64 / F;
    int wave = (blockIdx.x * blockDim.x + threadIdx.x) >> 6;
    int lane = threadIdx.x & 63;
    int n = wave * NPW + lane / F;
    int f = lane % F;
    if (n >= N_NODES) return;
    int start = row_ptr[n];
    int d = deg[n];
    const int* sr = sorted_row + start;
    float acc = hs[(long long)n * F + f];  // self-loop term
    int j = 0;
    for (; j + 4 <= d; j += 4) {
        int r0 = sr[j], r1 = sr[j + 1], r2 = sr[j + 2], r3 = sr[j + 3];
        float a0 = hs[(long long)r0 * F + f];
        float a1 = hs[(long long)r1 * F + f];
        float a2 = hs[(long long)r2 * F + f];
        float a3 = hs[(long long)r3 * F + f];
        acc += (a0 + a1) + (a2 + a3);
    }
    for (; j < d; j++) acc += hs[(long long)sr[j] * F + f];
    agg[(long long)n * F + f] = dis[n] * acc;
}

// ---------------- matmul + bias + DETERMINISTIC double-precision BN partials ----------------
// Fixed NB_STATS blocks, grid-stride; o = t % OUT is stride-invariant (stride % OUT == 0).
// Per-thread double sum/sumsq in fixed order -> deterministic block tree-reduce -> per-block
// partials in global memory (no atomics, no order sensitivity).
template <int IN, int OUT, int INSTRIDE>
__global__ void matmul_stats_kernel(const float* __restrict__ agg, const float* __restrict__ W,
                                    const float* __restrict__ b, float* __restrict__ pre,
                                    double* __restrict__ part_s, double* __restrict__ part_q) {
    __shared__ float Ws[IN * OUT];
    __shared__ double s_s[256];
    __shared__ double s_q[256];
    for (int k = threadIdx.x; k < IN * OUT; k += blockDim.x) Ws[k] = W[k];
    __syncthreads();
    const long long total = (long long)N_NODES * OUT;
    const long long stride = (long long)NB_STATS * 256;  // multiple of OUT
    long long t0 = (long long)blockIdx.x * 256 + threadIdx.x;
    int o = (int)(t0 % OUT);
    float bo = b[o];
    double my_s = 0.0, my_q = 0.0;
    for (long long t = t0; t < total; t += stride) {
        long long i = t / OUT;
        float acc = bo;
#pragma unroll
        for (int k = 0; k < IN; k++) acc += agg[i * INSTRIDE + k] * Ws[k * OUT + o];
        pre[t] = acc;
        my_s += (double)acc;
        my_q += (double)acc * (double)acc;
    }
    s_s[threadIdx.x] = my_s;
    s_q[threadIdx.x] = my_q;
    __syncthreads();
    // reduce entries with the same o (indices ≡ o mod OUT), deterministic order
    if (threadIdx.x < OUT) {
        double ts = 0.0, tq = 0.0;
        for (int k = threadIdx.x; k < 256; k += OUT) { ts += s_s[k]; tq += s_q[k]; }
        part_s[(long long)blockIdx.x * OUT + threadIdx.x] = ts;
        part_q[(long long)blockIdx.x * OUT + threadIdx.x] = tq;
    }
}

// ---------------- finalize BN stats: mean + rstd per feature (deterministic, double) ----------------
template <int OUT>
__global__ void bn_finalize_kernel(const double* __restrict__ part_s, const double* __restrict__ part_q,
                                   float* __restrict__ bn_mean, float* __restrict__ bn_rstd) {
    int o = threadIdx.x;
    if (o >= OUT) return;
    double s = 0.0, q = 0.0;
    for (int bb = 0; bb < NB_STATS; bb++) {
        s += part_s[(long long)bb * OUT + o];
        q += part_q[(long long)bb * OUT + o];
    }
    double mean = s / (double)N_NODES;
    double var = q / (double)N_NODES - mean * mean;
    bn_mean[o] = (float)mean;
    bn_rstd[o] = (float)(1.0 / sqrt(var + BN_EPS));
}

// ---------------- BN apply + ReLU (optionally pre-scale by dis for the next gather) ----------------
template <int F, bool SCALE>
__global__ void bn_relu_kernel(const float* __restrict__ pre, const float* __restrict__ bn_mean,
                               const float* __restrict__ bn_rstd, const float* __restrict__ g,
                               const float* __restrict__ be, const float* __restrict__ dis,
                               float* __restrict__ out) {
    int t = blockIdx.x * blockDim.x + threadIdx.x;
    const int total = N_NODES * F;
    if (t >= total) return;
    int f = t % F;
    float y = (pre[t] - bn_mean[f]) * bn_rstd[f] * g[f] + be[f];
    y = y > 0.f ? y : 0.f;
    if (SCALE) y *= dis[t / F];
    out[t] = y;
}

// ---------------- mean pool: one wave per 256-node chunk, lane = feature ----------------
#define POOL_CHUNK 256
__global__ void pool_kernel(const float* __restrict__ h, const int* __restrict__ batch,
                            float* __restrict__ pooled, float* __restrict__ cnt) {
    int lane = threadIdx.x;  // blockDim.x == 64
    int start = blockIdx.x * POOL_CHUNK;
    int end = start + POOL_CHUNK;
    if (end > N_NODES) end = N_NODES;
    if (start >= end) return;
    int cur = batch[start];
    float acc = 0.f;
    float c = 0.f;
    for (int i = start; i < end; i++) {
        int b = batch[i];  // broadcast
        if (b != cur) {
            atomicAdd(&pooled[cur * 64 + lane], acc);
            if (lane == 0) atomicAdd(&cnt[cur], c);
            acc = 0.f; c = 0.f; cur = b;
        }
        acc += h[(long long)i * 64 + lane];
        c += 1.f;
    }
    atomicAdd(&pooled[cur * 64 + lane], acc);
    if (lane == 0) atomicAdd(&cnt[cur], c);
}

// ---------------- final linear ----------------
__global__ void final_kernel(const float* __restrict__ pooled, const float* __restrict__ cnt,
                             const float* __restrict__ fcW, const float* __restrict__ fcb,
                             float* __restrict__ out) {
    int t = blockIdx.x * blockDim.x + threadIdx.x;
    if (t >= B_GRAPHS * 10) return;
    int b = t / 10, j = t % 10;
    float inv = 1.0f / fmaxf(cnt[b], 1.0f);
    float acc = fcb[j];
#pragma unroll
    for (int f = 0; f < 64; f++) acc += pooled[b * 64 + f] * inv * fcW[f * 10 + j];
    out[t] = acc;
}

extern "C" void kernel_launch(void* const* d_in, const int* in_sizes, int n_in,
                              void* d_out, int out_size, void* d_ws, size_t ws_size,
                              hipStream_t stream) {
    const float* x  = (const float*)d_in[0];
    const int* ei   = (const int*)d_in[1];
    const int* batch= (const int*)d_in[2];
    const float* W1 = (const float*)d_in[3];  const float* b1 = (const float*)d_in[4];
    const float* g1 = (const float*)d_in[5];  const float* be1= (const float*)d_in[6];
    const float* W2 = (const float*)d_in[7];  const float* b2 = (const float*)d_in[8];
    const float* g2 = (const float*)d_in[9];  const float* be2= (const float*)d_in[10];
    const float* W3 = (const float*)d_in[11]; const float* b3 = (const float*)d_in[12];
    const float* g3 = (const float*)d_in[13]; const float* be3= (const float*)d_in[14];
    const float* fcW= (const float*)d_in[15]; const float* fcb= (const float*)d_in[16];
    float* out = (float*)d_out;

    const int* row = ei;
    const int* col = ei + N_EDGES;

    // workspace layout
    char* wp = (char*)d_ws;
    float* dis       = (float*)wp;               wp += N_NODES * 4;
    int*   deg_i     = (int*)wp;                 wp += N_NODES * 4;
    int*   row_ptr   = (int*)wp;                 wp += N_NODES * 4;
    int*   pos       = (int*)wp;                 wp += N_NODES * 4;
    int*   bsum      = (int*)wp;                 wp += 512 * 4;
    int*   boff      = (int*)wp;                 wp += 512 * 4;
    int*   sorted_row= (int*)wp;                 wp += (size_t)N_EDGES * 4;
    double* part_s   = (double*)wp;              wp += (size_t)NB_STATS * 64 * 8;
    double* part_q   = (double*)wp;              wp += (size_t)NB_STATS * 64 * 8;
    float* bn_mean   = (float*)wp;               wp += 64 * 4;
    float* bn_rstd   = (float*)wp;               wp += 64 * 4;
    float* pooled    = (float*)wp;               wp += 64 * 64 * 4;
    float* cnt       = (float*)wp;               wp += 64 * 4;
    float* xs4       = (float*)wp;               wp += (size_t)N_NODES * 4 * 4;
    float* agg4      = (float*)wp;               wp += (size_t)N_NODES * 4 * 4;
    float* P         = (float*)wp;               wp += (size_t)N_NODES * 64 * 4;  // ping
    float* H         = (float*)wp;               wp += (size_t)N_NODES * 64 * 4;  // pong

    const int BS = 256;

    // ---- degree + dis + CSR build
    hipMemsetAsync(deg_i, 0, N_NODES * sizeof(int), stream);
    deg_kernel<<<cdiv(N_EDGES, BS), BS, 0, stream>>>(col, deg_i);
    dis_kernel<<<cdiv(N_NODES, BS), BS, 0, stream>>>(deg_i, dis);
    blocksum_kernel<<<NBLK, 256, 0, stream>>>(deg_i, bsum);
    scanbsum_kernel<<<1, 512, 0, stream>>>(bsum, boff);
    writeptr_kernel<<<NBLK, 256, 0, stream>>>(deg_i, boff, row_ptr, pos);
    scatter_kernel<<<cdiv(N_EDGES, BS), BS, 0, stream>>>(row, col, pos, sorted_row);

    // ---- layer 1: gather at F=4 (x padded), then 3->16 matmul
    scale_x_kernel<<<cdiv(N_NODES, BS), BS, 0, stream>>>(x, dis, xs4);
    gather_kernel<4><<<cdiv((long long)cdiv(N_NODES, 16) * 64, BS), BS, 0, stream>>>(
        row_ptr, deg_i, sorted_row, dis, xs4, agg4);
    matmul_stats_kernel<3, 16, 4><<<NB_STATS, 256, 0, stream>>>(agg4, W1, b1, P, part_s, part_q);
    bn_finalize_kernel<16><<<1, 64, 0, stream>>>(part_s, part_q, bn_mean, bn_rstd);
    bn_relu_kernel<16, true><<<cdiv((long long)N_NODES * 16, BS), BS, 0, stream>>>(
        P, bn_mean, bn_rstd, g1, be1, dis, H);  // H = h1 * dis

    // ---- layer 2: gather at F=16, then 16->32 matmul
    gather_kernel<16><<<cdiv((long long)cdiv(N_NODES, 4) * 64, BS), BS, 0, stream>>>(
        row_ptr, deg_i, sorted_row, dis, H, P);  // P = agg16
    matmul_stats_kernel<16, 32, 16><<<NB_STATS, 256, 0, stream>>>(P, W2, b2, H, part_s, part_q);
    bn_finalize_kernel<32><<<1, 64, 0, stream>>>(part_s, part_q, bn_mean, bn_rstd);
    bn_relu_kernel<32, true><<<cdiv((long long)N_NODES * 32, BS), BS, 0, stream>>>(
        H, bn_mean, bn_rstd, g2, be2, dis, P);  // P = h2 * dis

    // ---- layer 3: gather at F=32, then 32->64 matmul
    gather_kernel<32><<<cdiv((long long)cdiv(N_NODES, 2) * 64, BS), BS, 0, stream>>>(
        row_ptr, deg_i, sorted_row, dis, P, H);  // H = agg32
    matmul_stats_kernel<32, 64, 32><<<NB_STATS, 256, 0, stream>>>(H, W3, b3, P, part_s, part_q);
    bn_finalize_kernel<64><<<1, 64, 0, stream>>>(part_s, part_q, bn_mean, bn_rstd);
    bn_relu_kernel<64, false><<<cdiv((long long)N_NODES * 64, BS), BS, 0, stream>>>(
        P, bn_mean, bn_rstd, g3, be3, dis, H);  // H = h3

    // ---- pool + fc
    hipMemsetAsync(pooled, 0, (64 * 64 + 64) * sizeof(float), stream);
    pool_kernel<<<cdiv(N_NODES, POOL_CHUNK), 64, 0, stream>>>(H, batch, pooled, cnt);
    final_kernel<<<1, B_GRAPHS * 10, 0, stream>>>(pooled, cnt, fcW, fcb, out);
}

// Round 7
// 542.796 us; speedup vs baseline: 6.3986x; 1.2502x over previous
//
#include <hip/hip_runtime.h>

#define N_NODES 100000
#define N_EDGES 1600000
#define B_GRAPHS 64
#define BN_EPS 1e-5
#define NBLK 391      // cdiv(N_NODES, 256)
#define NB_STATS 1024 // blocks for matmul+stats kernels

static inline int cdiv(long long a, int b) { return (int)((a + b - 1) / b); }

// ---------------- degree histogram (int) ----------------
__global__ void deg_kernel(const int* __restrict__ col, int* __restrict__ deg) {
    int t = blockIdx.x * blockDim.x + threadIdx.x;
    if (t < N_EDGES) atomicAdd(&deg[col[t]], 1);
}

__global__ void dis_kernel(const int* __restrict__ deg, float* __restrict__ dis) {
    int i = blockIdx.x * blockDim.x + threadIdx.x;
    if (i < N_NODES) dis[i] = rsqrtf((float)deg[i] + 1.0f);  // +1 = self-loop
}

// ---------------- CSR build: two-level exclusive scan of deg ----------------
__global__ void blocksum_kernel(const int* __restrict__ deg, int* __restrict__ bsum) {
    __shared__ int s[256];
    int i = blockIdx.x * 256 + threadIdx.x;
    s[threadIdx.x] = (i < N_NODES) ? deg[i] : 0;
    __syncthreads();
    for (int off = 128; off > 0; off >>= 1) {
        if (threadIdx.x < off) s[threadIdx.x] += s[threadIdx.x + off];
        __syncthreads();
    }
    if (threadIdx.x == 0) bsum[blockIdx.x] = s[0];
}

__global__ void scanbsum_kernel(const int* __restrict__ bsum, int* __restrict__ boff) {
    __shared__ int s[512];
    int t = threadIdx.x;
    int v0 = (t < NBLK) ? bsum[t] : 0;
    s[t] = v0;
    __syncthreads();
    for (int off = 1; off < 512; off <<= 1) {
        int v = (t >= off) ? s[t - off] : 0;
        __syncthreads();
        s[t] += v;
        __syncthreads();
    }
    if (t < NBLK) boff[t] = s[t] - v0;  // exclusive
}

__global__ void writeptr_kernel(const int* __restrict__ deg, const int* __restrict__ boff,
                                int* __restrict__ row_ptr, int* __restrict__ pos) {
    __shared__ int s[256];
    int i = blockIdx.x * 256 + threadIdx.x;
    int d = (i < N_NODES) ? deg[i] : 0;
    s[threadIdx.x] = d;
    __syncthreads();
    for (int off = 1; off < 256; off <<= 1) {
        int v = (threadIdx.x >= off) ? s[threadIdx.x - off] : 0;
        __syncthreads();
        s[threadIdx.x] += v;
        __syncthreads();
    }
    if (i < N_NODES) {
        int p = boff[blockIdx.x] + s[threadIdx.x] - d;  // exclusive
        row_ptr[i] = p;
        pos[i] = p;
    }
}

__global__ void scatter_kernel(const int* __restrict__ row, const int* __restrict__ col,
                               int* __restrict__ pos, int* __restrict__ sorted_row) {
    int t = blockIdx.x * blockDim.x + threadIdx.x;
    if (t < N_EDGES) {
        int c = col[t];
        int p = atomicAdd(&pos[c], 1);
        sorted_row[p] = row[t];
    }
}

// ---------------- pre-scale x by dis, pad 3 -> 4 ----------------
__global__ void scale_x_kernel(const float* __restrict__ x, const float* __restrict__ dis,
                               float* __restrict__ xs4) {
    int i = blockIdx.x * blockDim.x + threadIdx.x;
    if (i < N_NODES) {
        float d = dis[i];
        xs4[i * 4 + 0] = x[i * 3 + 0] * d;
        xs4[i * 4 + 1] = x[i * 3 + 1] * d;
        xs4[i * 4 + 2] = x[i * 3 + 2] * d;
        xs4[i * 4 + 3] = 0.f;
    }
}

// ---------------- CSR gather at width F: agg[n] = dis[n] * (sum_{r in in(n)} hs[r] + hs[n]) ----------------
template <int F>
__global__ void gather_kernel(const int* __restrict__ row_ptr, const int* __restrict__ deg,
                              const int* __restrict__ sorted_row, const float* __restrict__ dis,
                              const float* __restrict__ hs, float* __restrict__ agg) {
    const int NPW = 64 / F;
    int wave = (blockIdx.x * blockDim.x + threadIdx.x) >> 6;
    int lane = threadIdx.x & 63;
    int n = wave * NPW + lane / F;
    int f = lane % F;
    if (n >= N_NODES) return;
    int start = row_ptr[n];
    int d = deg[n];
    const int* sr = sorted_row + start;
    float acc = hs[(long long)n * F + f];  // self-loop term
    int j = 0;
    for (; j + 4 <= d; j += 4) {
        int r0 = sr[j], r1 = sr[j + 1], r2 = sr[j + 2], r3 = sr[j + 3];
        float a0 = hs[(long long)r0 * F + f];
        float a1 = hs[(long long)r1 * F + f];
        float a2 = hs[(long long)r2 * F + f];
        float a3 = hs[(long long)r3 * F + f];
        acc += (a0 + a1) + (a2 + a3);
    }
    for (; j < d; j++) acc += hs[(long long)sr[j] * F + f];
    agg[(long long)n * F + f] = dis[n] * acc;
}

// ---------------- matmul + bias + deterministic fp64 BN partials ----------------
// Partials stored TRANSPOSED: part[o * NB_STATS + blockIdx] so finalize reads contiguously.
template <int IN, int OUT, int INSTRIDE>
__global__ void matmul_stats_kernel(const float* __restrict__ agg, const float* __restrict__ W,
                                    const float* __restrict__ b, float* __restrict__ pre,
                                    double* __restrict__ part_s, double* __restrict__ part_q) {
    __shared__ float Ws[IN * OUT];
    __shared__ double s_s[256];
    __shared__ double s_q[256];
    for (int k = threadIdx.x; k < IN * OUT; k += blockDim.x) Ws[k] = W[k];
    __syncthreads();
    const long long total = (long long)N_NODES * OUT;
    const long long stride = (long long)NB_STATS * 256;  // multiple of OUT
    long long t0 = (long long)blockIdx.x * 256 + threadIdx.x;
    int o = (int)(t0 % OUT);
    float bo = b[o];
    double my_s = 0.0, my_q = 0.0;
    for (long long t = t0; t < total; t += stride) {
        long long i = t / OUT;
        float acc = bo;
#pragma unroll
        for (int k = 0; k < IN; k++) acc += agg[i * INSTRIDE + k] * Ws[k * OUT + o];
        pre[t] = acc;
        my_s += (double)acc;
        my_q += (double)acc * (double)acc;
    }
    s_s[threadIdx.x] = my_s;
    s_q[threadIdx.x] = my_q;
    __syncthreads();
    // combine lanes with the same o (indices ≡ o mod OUT), fixed order -> deterministic
    if (threadIdx.x < OUT) {
        double ts = 0.0, tq = 0.0;
        for (int k = threadIdx.x; k < 256; k += OUT) { ts += s_s[k]; tq += s_q[k]; }
        part_s[(long long)threadIdx.x * NB_STATS + blockIdx.x] = ts;
        part_q[(long long)threadIdx.x * NB_STATS + blockIdx.x] = tq;
    }
}

// ---------------- finalize BN stats: one block per feature, coalesced + deterministic ----------------
__global__ void bn_finalize_kernel(const double* __restrict__ part_s, const double* __restrict__ part_q,
                                   float* __restrict__ bn_mean, float* __restrict__ bn_rstd) {
    __shared__ double s_s[256];
    __shared__ double s_q[256];
    int o = blockIdx.x;
    int t = threadIdx.x;
    double ms = 0.0, mq = 0.0;
#pragma unroll
    for (int k = 0; k < NB_STATS / 256; k++) {
        ms += part_s[(long long)o * NB_STATS + k * 256 + t];
        mq += part_q[(long long)o * NB_STATS + k * 256 + t];
    }
    s_s[t] = ms;
    s_q[t] = mq;
    __syncthreads();
    for (int off = 128; off > 0; off >>= 1) {
        if (t < off) { s_s[t] += s_s[t + off]; s_q[t] += s_q[t + off]; }
        __syncthreads();
    }
    if (t == 0) {
        double mean = s_s[0] / (double)N_NODES;
        double var = s_q[0] / (double)N_NODES - mean * mean;
        bn_mean[o] = (float)mean;
        bn_rstd[o] = (float)(1.0 / sqrt(var + BN_EPS));
    }
}

// ---------------- BN apply + ReLU (optionally pre-scale by dis for the next gather) ----------------
template <int F, bool SCALE>
__global__ void bn_relu_kernel(const float* __restrict__ pre, const float* __restrict__ bn_mean,
                               const float* __restrict__ bn_rstd, const float* __restrict__ g,
                               const float* __restrict__ be, const float* __restrict__ dis,
                               float* __restrict__ out) {
    int t = blockIdx.x * blockDim.x + threadIdx.x;
    const int total = N_NODES * F;
    if (t >= total) return;
    int f = t % F;
    float y = (pre[t] - bn_mean[f]) * bn_rstd[f] * g[f] + be[f];
    y = y > 0.f ? y : 0.f;
    if (SCALE) y *= dis[t / F];
    out[t] = y;
}

// ---------------- mean pool: one wave per 256-node chunk, lane = feature ----------------
#define POOL_CHUNK 256
__global__ void pool_kernel(const float* __restrict__ h, const int* __restrict__ batch,
                            float* __restrict__ pooled, float* __restrict__ cnt) {
    int lane = threadIdx.x;  // blockDim.x == 64
    int start = blockIdx.x * POOL_CHUNK;
    int end = start + POOL_CHUNK;
    if (end > N_NODES) end = N_NODES;
    if (start >= end) return;
    int cur = batch[start];
    float acc = 0.f;
    float c = 0.f;
    for (int i = start; i < end; i++) {
        int b = batch[i];  // broadcast
        if (b != cur) {
            atomicAdd(&pooled[cur * 64 + lane], acc);
            if (lane == 0) atomicAdd(&cnt[cur], c);
            acc = 0.f; c = 0.f; cur = b;
        }
        acc += h[(long long)i * 64 + lane];
        c += 1.f;
    }
    atomicAdd(&pooled[cur * 64 + lane], acc);
    if (lane == 0) atomicAdd(&cnt[cur], c);
}

// ---------------- final linear ----------------
__global__ void final_kernel(const float* __restrict__ pooled, const float* __restrict__ cnt,
                             const float* __restrict__ fcW, const float* __restrict__ fcb,
                             float* __restrict__ out) {
    int t = blockIdx.x * blockDim.x + threadIdx.x;
    if (t >= B_GRAPHS * 10) return;
    int b = t / 10, j = t % 10;
    float inv = 1.0f / fmaxf(cnt[b], 1.0f);
    float acc = fcb[j];
#pragma unroll
    for (int f = 0; f < 64; f++) acc += pooled[b * 64 + f] * inv * fcW[f * 10 + j];
    out[t] = acc;
}

extern "C" void kernel_launch(void* const* d_in, const int* in_sizes, int n_in,
                              void* d_out, int out_size, void* d_ws, size_t ws_size,
                              hipStream_t stream) {
    const float* x  = (const float*)d_in[0];
    const int* ei   = (const int*)d_in[1];
    const int* batch= (const int*)d_in[2];
    const float* W1 = (const float*)d_in[3];  const float* b1 = (const float*)d_in[4];
    const float* g1 = (const float*)d_in[5];  const float* be1= (const float*)d_in[6];
    const float* W2 = (const float*)d_in[7];  const float* b2 = (const float*)d_in[8];
    const float* g2 = (const float*)d_in[9];  const float* be2= (const float*)d_in[10];
    const float* W3 = (const float*)d_in[11]; const float* b3 = (const float*)d_in[12];
    const float* g3 = (const float*)d_in[13]; const float* be3= (const float*)d_in[14];
    const float* fcW= (const float*)d_in[15]; const float* fcb= (const float*)d_in[16];
    float* out = (float*)d_out;

    const int* row = ei;
    const int* col = ei + N_EDGES;

    // workspace layout
    char* wp = (char*)d_ws;
    float* dis       = (float*)wp;               wp += N_NODES * 4;
    int*   deg_i     = (int*)wp;                 wp += N_NODES * 4;
    int*   row_ptr   = (int*)wp;                 wp += N_NODES * 4;
    int*   pos       = (int*)wp;                 wp += N_NODES * 4;
    int*   bsum      = (int*)wp;                 wp += 512 * 4;
    int*   boff      = (int*)wp;                 wp += 512 * 4;
    int*   sorted_row= (int*)wp;                 wp += (size_t)N_EDGES * 4;
    double* part_s   = (double*)wp;              wp += (size_t)NB_STATS * 64 * 8;
    double* part_q   = (double*)wp;              wp += (size_t)NB_STATS * 64 * 8;
    float* bn_mean   = (float*)wp;               wp += 64 * 4;
    float* bn_rstd   = (float*)wp;               wp += 64 * 4;
    float* pooled    = (float*)wp;               wp += 64 * 64 * 4;
    float* cnt       = (float*)wp;               wp += 64 * 4;
    float* xs4       = (float*)wp;               wp += (size_t)N_NODES * 4 * 4;
    float* agg4      = (float*)wp;               wp += (size_t)N_NODES * 4 * 4;
    float* P         = (float*)wp;               wp += (size_t)N_NODES * 64 * 4;  // ping
    float* H         = (float*)wp;               wp += (size_t)N_NODES * 64 * 4;  // pong

    const int BS = 256;

    // ---- degree + dis + CSR build
    hipMemsetAsync(deg_i, 0, N_NODES * sizeof(int), stream);
    deg_kernel<<<cdiv(N_EDGES, BS), BS, 0, stream>>>(col, deg_i);
    dis_kernel<<<cdiv(N_NODES, BS), BS, 0, stream>>>(deg_i, dis);
    blocksum_kernel<<<NBLK, 256, 0, stream>>>(deg_i, bsum);
    scanbsum_kernel<<<1, 512, 0, stream>>>(bsum, boff);
    writeptr_kernel<<<NBLK, 256, 0, stream>>>(deg_i, boff, row_ptr, pos);
    scatter_kernel<<<cdiv(N_EDGES, BS), BS, 0, stream>>>(row, col, pos, sorted_row);

    // ---- layer 1: gather at F=4 (x padded), then 3->16 matmul
    scale_x_kernel<<<cdiv(N_NODES, BS), BS, 0, stream>>>(x, dis, xs4);
    gather_kernel<4><<<cdiv((long long)cdiv(N_NODES, 16) * 64, BS), BS, 0, stream>>>(
        row_ptr, deg_i, sorted_row, dis, xs4, agg4);
    matmul_stats_kernel<3, 16, 4><<<NB_STATS, 256, 0, stream>>>(agg4, W1, b1, P, part_s, part_q);
    bn_finalize_kernel<<<16, 256, 0, stream>>>(part_s, part_q, bn_mean, bn_rstd);
    bn_relu_kernel<16, true><<<cdiv((long long)N_NODES * 16, BS), BS, 0, stream>>>(
        P, bn_mean, bn_rstd, g1, be1, dis, H);  // H = h1 * dis

    // ---- layer 2: gather at F=16, then 16->32 matmul
    gather_kernel<16><<<cdiv((long long)cdiv(N_NODES, 4) * 64, BS), BS, 0, stream>>>(
        row_ptr, deg_i, sorted_row, dis, H, P);  // P = agg16
    matmul_stats_kernel<16, 32, 16><<<NB_STATS, 256, 0, stream>>>(P, W2, b2, H, part_s, part_q);
    bn_finalize_kernel<<<32, 256, 0, stream>>>(part_s, part_q, bn_mean, bn_rstd);
    bn_relu_kernel<32, true><<<cdiv((long long)N_NODES * 32, BS), BS, 0, stream>>>(
        H, bn_mean, bn_rstd, g2, be2, dis, P);  // P = h2 * dis

    // ---- layer 3: gather at F=32, then 32->64 matmul
    gather_kernel<32><<<cdiv((long long)cdiv(N_NODES, 2) * 64, BS), BS, 0, stream>>>(
        row_ptr, deg_i, sorted_row, dis, P, H);  // H = agg32
    matmul_stats_kernel<32, 64, 32><<<NB_STATS, 256, 0, stream>>>(H, W3, b3, P, part_s, part_q);
    bn_finalize_kernel<<<64, 256, 0, stream>>>(part_s, part_q, bn_mean, bn_rstd);
    bn_relu_kernel<64, false><<<cdiv((long long)N_NODES * 64, BS), BS, 0, stream>>>(
        P, bn_mean, bn_rstd, g3, be3, dis, H);  // H = h3

    // ---- pool + fc
    hipMemsetAsync(pooled, 0, (64 * 64 + 64) * sizeof(float), stream);
    pool_kernel<<<cdiv(N_NODES, POOL_CHUNK), 64, 0, stream>>>(H, batch, pooled, cnt);
    final_kernel<<<1, B_GRAPHS * 10, 0, stream>>>(pooled, cnt, fcW, fcb, out);
}

// Round 8
// 395.207 us; speedup vs baseline: 8.7882x; 1.3734x over previous
//
#include <hip/hip_runtime.h>

#define N_NODES 100000
#define N_EDGES 1600000
#define B_GRAPHS 64
#define BN_EPS 1e-5
#define NB_STATS 1024 // blocks for matmul+stats kernels

#define NBUCK 256
#define BUCK_NODES 392   // 256*392 = 100352 >= N_NODES
#define PART_CHUNK 4096
#define NB_PART 391      // cdiv(N_EDGES, PART_CHUNK)

static inline int cdiv(long long a, int b) { return (int)((a + b - 1) / b); }

// ---------------- phase 1: bucket histogram of col ----------------
__global__ void part_hist_kernel(const int* __restrict__ col, int* __restrict__ bucket_cnt) {
    __shared__ int h[NBUCK];
    for (int i = threadIdx.x; i < NBUCK; i += 256) h[i] = 0;
    __syncthreads();
    long long ebase = (long long)blockIdx.x * PART_CHUNK;
    int n = (N_EDGES - ebase < PART_CHUNK) ? (int)(N_EDGES - ebase) : PART_CHUNK;
    for (int i = threadIdx.x; i < n; i += 256)
        atomicAdd(&h[col[ebase + i] / BUCK_NODES], 1);
    __syncthreads();
    for (int i = threadIdx.x; i < NBUCK; i += 256)
        if (h[i]) atomicAdd(&bucket_cnt[i], h[i]);
}

// ---------------- phase 2: scan bucket counts -> base & cursor ----------------
__global__ void part_scan_kernel(const int* __restrict__ bucket_cnt, int* __restrict__ bucket_base,
                                 int* __restrict__ bucket_cur) {
    __shared__ int s[NBUCK];
    int t = threadIdx.x;
    int v = bucket_cnt[t];
    s[t] = v;
    __syncthreads();
    for (int off = 1; off < NBUCK; off <<= 1) {
        int u = (t >= off) ? s[t - off] : 0;
        __syncthreads();
        s[t] += u;
        __syncthreads();
    }
    bucket_base[t] = s[t] - v;  // exclusive
    bucket_cur[t] = s[t] - v;
}

// ---------------- phase 3: partition edges into bucket-contiguous (row,col) pairs ----------------
__global__ void part_scatter_kernel(const int* __restrict__ row, const int* __restrict__ col,
                                    int* __restrict__ bucket_cur, int2* __restrict__ part_edges) {
    __shared__ int h[NBUCK];
    __shared__ int base_s[NBUCK];
    __shared__ int cur_s[NBUCK];
    long long ebase = (long long)blockIdx.x * PART_CHUNK;
    int n = (N_EDGES - ebase < PART_CHUNK) ? (int)(N_EDGES - ebase) : PART_CHUNK;
    for (int i = threadIdx.x; i < NBUCK; i += 256) h[i] = 0;
    __syncthreads();
    for (int i = threadIdx.x; i < n; i += 256)
        atomicAdd(&h[col[ebase + i] / BUCK_NODES], 1);
    __syncthreads();
    for (int i = threadIdx.x; i < NBUCK; i += 256) {
        int c = h[i];
        base_s[i] = c ? atomicAdd(&bucket_cur[i], c) : 0;
        cur_s[i] = 0;
    }
    __syncthreads();
    for (int i = threadIdx.x; i < n; i += 256) {
        int r = row[ebase + i], c = col[ebase + i];
        int bkt = c / BUCK_NODES;
        int p = base_s[bkt] + atomicAdd(&cur_s[bkt], 1);
        part_edges[p] = make_int2(r, c);
    }
}

// ---------------- phase 4: per-bucket CSR build (one block owns one bucket) ----------------
// LDS histogram over the bucket's 392 nodes -> LDS scan -> row_ptr/deg/dis -> LDS-cursor scatter.
// All sorted_row writes for a bucket come from ONE CU -> no cross-XCD line bouncing.
__global__ void csr_build_kernel(const int* __restrict__ bucket_base, const int2* __restrict__ part_edges,
                                 int* __restrict__ row_ptr, int* __restrict__ deg,
                                 float* __restrict__ dis, int* __restrict__ sorted_row) {
    __shared__ int hist[BUCK_NODES];  // histogram, then reused as scatter cursors
    __shared__ int tsum[256];
    int b = blockIdx.x;
    int t = threadIdx.x;
    int nbase = b * BUCK_NODES;
    int ebase = bucket_base[b];
    int eend = (b == NBUCK - 1) ? N_EDGES : bucket_base[b + 1];
    int ne = eend - ebase;
    for (int i = t; i < BUCK_NODES; i += 256) hist[i] = 0;
    __syncthreads();
    for (int i = t; i < ne; i += 256)
        atomicAdd(&hist[part_edges[ebase + i].y - nbase], 1);
    __syncthreads();
    // exclusive scan of hist: 2 elements per thread (t < 196), then block scan of totals
    int a0 = 0, a1 = 0;
    if (t < BUCK_NODES / 2) { a0 = hist[2 * t]; a1 = hist[2 * t + 1]; tsum[t] = a0 + a1; }
    else tsum[t] = 0;
    __syncthreads();
    for (int off = 1; off < 256; off <<= 1) {
        int u = (t >= off) ? tsum[t - off] : 0;
        __syncthreads();
        tsum[t] += u;
        __syncthreads();
    }
    if (t < BUCK_NODES / 2) {
        int excl = tsum[t] - (a0 + a1);
        hist[2 * t] = excl;            // cursor for node 2t
        hist[2 * t + 1] = excl + a0;   // cursor for node 2t+1
        int n0 = nbase + 2 * t, n1 = n0 + 1;
        if (n0 < N_NODES) {
            row_ptr[n0] = ebase + excl;
            deg[n0] = a0;
            dis[n0] = rsqrtf((float)a0 + 1.0f);
        }
        if (n1 < N_NODES) {
            row_ptr[n1] = ebase + excl + a0;
            deg[n1] = a1;
            dis[n1] = rsqrtf((float)a1 + 1.0f);
        }
    }
    __syncthreads();
    for (int i = t; i < ne; i += 256) {
        int2 e = part_edges[ebase + i];
        int p = atomicAdd(&hist[e.y - nbase], 1);
        sorted_row[ebase + p] = e.x;
    }
}

// ---------------- pre-scale x by dis, pad 3 -> 4 ----------------
__global__ void scale_x_kernel(const float* __restrict__ x, const float* __restrict__ dis,
                               float* __restrict__ xs4) {
    int i = blockIdx.x * blockDim.x + threadIdx.x;
    if (i < N_NODES) {
        float d = dis[i];
        xs4[i * 4 + 0] = x[i * 3 + 0] * d;
        xs4[i * 4 + 1] = x[i * 3 + 1] * d;
        xs4[i * 4 + 2] = x[i * 3 + 2] * d;
        xs4[i * 4 + 3] = 0.f;
    }
}

// ---------------- CSR gather at width F: agg[n] = dis[n] * (sum_{r in in(n)} hs[r] + hs[n]) ----------------
template <int F>
__global__ void gather_kernel(const int* __restrict__ row_ptr, const int* __restrict__ deg,
                              const int* __restrict__ sorted_row, const float* __restrict__ dis,
                              const float* __restrict__ hs, float* __restrict__ agg) {
    const int NPW = 64 / F;
    int wave = (blockIdx.x * blockDim.x + threadIdx.x) >> 6;
    int lane = threadIdx.x & 63;
    int n = wave * NPW + lane / F;
    int f = lane % F;
    if (n >= N_NODES) return;
    int start = row_ptr[n];
    int d = deg[n];
    const int* sr = sorted_row + start;
    float acc = hs[(long long)n * F + f];  // self-loop term
    int j = 0;
    for (; j + 4 <= d; j += 4) {
        int r0 = sr[j], r1 = sr[j + 1], r2 = sr[j + 2], r3 = sr[j + 3];
        float a0 = hs[(long long)r0 * F + f];
        float a1 = hs[(long long)r1 * F + f];
        float a2 = hs[(long long)r2 * F + f];
        float a3 = hs[(long long)r3 * F + f];
        acc += (a0 + a1) + (a2 + a3);
    }
    for (; j < d; j++) acc += hs[(long long)sr[j] * F + f];
    agg[(long long)n * F + f] = dis[n] * acc;
}

// ---------------- matmul + bias + deterministic fp64 BN partials (transposed layout) ----------------
template <int IN, int OUT, int INSTRIDE>
__global__ void matmul_stats_kernel(const float* __restrict__ agg, const float* __restrict__ W,
                                    const float* __restrict__ b, float* __restrict__ pre,
                                    double* __restrict__ part_s, double* __restrict__ part_q) {
    __shared__ float Ws[IN * OUT];
    __shared__ double s_s[256];
    __shared__ double s_q[256];
    for (int k = threadIdx.x; k < IN * OUT; k += blockDim.x) Ws[k] = W[k];
    __syncthreads();
    const long long total = (long long)N_NODES * OUT;
    const long long stride = (long long)NB_STATS * 256;  // multiple of OUT
    long long t0 = (long long)blockIdx.x * 256 + threadIdx.x;
    int o = (int)(t0 % OUT);
    float bo = b[o];
    double my_s = 0.0, my_q = 0.0;
    for (long long t = t0; t < total; t += stride) {
        long long i = t / OUT;
        float acc = bo;
#pragma unroll
        for (int k = 0; k < IN; k++) acc += agg[i * INSTRIDE + k] * Ws[k * OUT + o];
        pre[t] = acc;
        my_s += (double)acc;
        my_q += (double)acc * (double)acc;
    }
    s_s[threadIdx.x] = my_s;
    s_q[threadIdx.x] = my_q;
    __syncthreads();
    if (threadIdx.x < OUT) {
        double ts = 0.0, tq = 0.0;
        for (int k = threadIdx.x; k < 256; k += OUT) { ts += s_s[k]; tq += s_q[k]; }
        part_s[(long long)threadIdx.x * NB_STATS + blockIdx.x] = ts;
        part_q[(long long)threadIdx.x * NB_STATS + blockIdx.x] = tq;
    }
}

// ---------------- finalize BN stats: one block per feature ----------------
__global__ void bn_finalize_kernel(const double* __restrict__ part_s, const double* __restrict__ part_q,
                                   float* __restrict__ bn_mean, float* __restrict__ bn_rstd) {
    __shared__ double s_s[256];
    __shared__ double s_q[256];
    int o = blockIdx.x;
    int t = threadIdx.x;
    double ms = 0.0, mq = 0.0;
#pragma unroll
    for (int k = 0; k < NB_STATS / 256; k++) {
        ms += part_s[(long long)o * NB_STATS + k * 256 + t];
        mq += part_q[(long long)o * NB_STATS + k * 256 + t];
    }
    s_s[t] = ms;
    s_q[t] = mq;
    __syncthreads();
    for (int off = 128; off > 0; off >>= 1) {
        if (t < off) { s_s[t] += s_s[t + off]; s_q[t] += s_q[t + off]; }
        __syncthreads();
    }
    if (t == 0) {
        double mean = s_s[0] / (double)N_NODES;
        double var = s_q[0] / (double)N_NODES - mean * mean;
        bn_mean[o] = (float)mean;
        bn_rstd[o] = (float)(1.0 / sqrt(var + BN_EPS));
    }
}

// ---------------- BN apply + ReLU (optionally pre-scale by dis for the next gather) ----------------
template <int F, bool SCALE>
__global__ void bn_relu_kernel(const float* __restrict__ pre, const float* __restrict__ bn_mean,
                               const float* __restrict__ bn_rstd, const float* __restrict__ g,
                               const float* __restrict__ be, const float* __restrict__ dis,
                               float* __restrict__ out) {
    int t = blockIdx.x * blockDim.x + threadIdx.x;
    const int total = N_NODES * F;
    if (t >= total) return;
    int f = t % F;
    float y = (pre[t] - bn_mean[f]) * bn_rstd[f] * g[f] + be[f];
    y = y > 0.f ? y : 0.f;
    if (SCALE) y *= dis[t / F];
    out[t] = y;
}

// ---------------- mean pool: one wave per 256-node chunk, lane = feature ----------------
#define POOL_CHUNK 256
__global__ void pool_kernel(const float* __restrict__ h, const int* __restrict__ batch,
                            float* __restrict__ pooled, float* __restrict__ cnt) {
    int lane = threadIdx.x;  // blockDim.x == 64
    int start = blockIdx.x * POOL_CHUNK;
    int end = start + POOL_CHUNK;
    if (end > N_NODES) end = N_NODES;
    if (start >= end) return;
    int cur = batch[start];
    float acc = 0.f;
    float c = 0.f;
    for (int i = start; i < end; i++) {
        int b = batch[i];  // broadcast
        if (b != cur) {
            atomicAdd(&pooled[cur * 64 + lane], acc);
            if (lane == 0) atomicAdd(&cnt[cur], c);
            acc = 0.f; c = 0.f; cur = b;
        }
        acc += h[(long long)i * 64 + lane];
        c += 1.f;
    }
    atomicAdd(&pooled[cur * 64 + lane], acc);
    if (lane == 0) atomicAdd(&cnt[cur], c);
}

// ---------------- final linear ----------------
__global__ void final_kernel(const float* __restrict__ pooled, const float* __restrict__ cnt,
                             const float* __restrict__ fcW, const float* __restrict__ fcb,
                             float* __restrict__ out) {
    int t = blockIdx.x * blockDim.x + threadIdx.x;
    if (t >= B_GRAPHS * 10) return;
    int b = t / 10, j = t % 10;
    float inv = 1.0f / fmaxf(cnt[b], 1.0f);
    float acc = fcb[j];
#pragma unroll
    for (int f = 0; f < 64; f++) acc += pooled[b * 64 + f] * inv * fcW[f * 10 + j];
    out[t] = acc;
}

extern "C" void kernel_launch(void* const* d_in, const int* in_sizes, int n_in,
                              void* d_out, int out_size, void* d_ws, size_t ws_size,
                              hipStream_t stream) {
    const float* x  = (const float*)d_in[0];
    const int* ei   = (const int*)d_in[1];
    const int* batch= (const int*)d_in[2];
    const float* W1 = (const float*)d_in[3];  const float* b1 = (const float*)d_in[4];
    const float* g1 = (const float*)d_in[5];  const float* be1= (const float*)d_in[6];
    const float* W2 = (const float*)d_in[7];  const float* b2 = (const float*)d_in[8];
    const float* g2 = (const float*)d_in[9];  const float* be2= (const float*)d_in[10];
    const float* W3 = (const float*)d_in[11]; const float* b3 = (const float*)d_in[12];
    const float* g3 = (const float*)d_in[13]; const float* be3= (const float*)d_in[14];
    const float* fcW= (const float*)d_in[15]; const float* fcb= (const float*)d_in[16];
    float* out = (float*)d_out;

    const int* row = ei;
    const int* col = ei + N_EDGES;

    // workspace layout
    char* wp = (char*)d_ws;
    float* dis        = (float*)wp;              wp += N_NODES * 4;
    int*   deg_i      = (int*)wp;                wp += N_NODES * 4;
    int*   row_ptr    = (int*)wp;                wp += N_NODES * 4;
    int*   bucket_cnt = (int*)wp;                wp += NBUCK * 4;
    int*   bucket_base= (int*)wp;                wp += NBUCK * 4;
    int*   bucket_cur = (int*)wp;                wp += NBUCK * 4;
    int*   sorted_row = (int*)wp;                wp += (size_t)N_EDGES * 4;
    int2*  part_edges = (int2*)wp;               wp += (size_t)N_EDGES * 8;
    double* part_s    = (double*)wp;             wp += (size_t)NB_STATS * 64 * 8;
    double* part_q    = (double*)wp;             wp += (size_t)NB_STATS * 64 * 8;
    float* bn_mean    = (float*)wp;              wp += 64 * 4;
    float* bn_rstd    = (float*)wp;              wp += 64 * 4;
    float* pooled     = (float*)wp;              wp += 64 * 64 * 4;
    float* cnt        = (float*)wp;              wp += 64 * 4;
    float* xs4        = (float*)wp;              wp += (size_t)N_NODES * 4 * 4;
    float* agg4       = (float*)wp;              wp += (size_t)N_NODES * 4 * 4;
    float* P          = (float*)wp;              wp += (size_t)N_NODES * 64 * 4;  // ping
    float* H          = (float*)wp;              wp += (size_t)N_NODES * 64 * 4;  // pong

    const int BS = 256;

    // ---- CSR build: bucketed two-phase (no cross-XCD scatter)
    hipMemsetAsync(bucket_cnt, 0, NBUCK * sizeof(int), stream);
    part_hist_kernel<<<NB_PART, 256, 0, stream>>>(col, bucket_cnt);
    part_scan_kernel<<<1, NBUCK, 0, stream>>>(bucket_cnt, bucket_base, bucket_cur);
    part_scatter_kernel<<<NB_PART, 256, 0, stream>>>(row, col, bucket_cur, part_edges);
    csr_build_kernel<<<NBUCK, 256, 0, stream>>>(bucket_base, part_edges, row_ptr, deg_i, dis, sorted_row);

    // ---- layer 1: gather at F=4 (x padded), then 3->16 matmul
    scale_x_kernel<<<cdiv(N_NODES, BS), BS, 0, stream>>>(x, dis, xs4);
    gather_kernel<4><<<cdiv((long long)cdiv(N_NODES, 16) * 64, BS), BS, 0, stream>>>(
        row_ptr, deg_i, sorted_row, dis, xs4, agg4);
    matmul_stats_kernel<3, 16, 4><<<NB_STATS, 256, 0, stream>>>(agg4, W1, b1, P, part_s, part_q);
    bn_finalize_kernel<<<16, 256, 0, stream>>>(part_s, part_q, bn_mean, bn_rstd);
    bn_relu_kernel<16, true><<<cdiv((long long)N_NODES * 16, BS), BS, 0, stream>>>(
        P, bn_mean, bn_rstd, g1, be1, dis, H);  // H = h1 * dis

    // ---- layer 2: gather at F=16, then 16->32 matmul
    gather_kernel<16><<<cdiv((long long)cdiv(N_NODES, 4) * 64, BS), BS, 0, stream>>>(
        row_ptr, deg_i, sorted_row, dis, H, P);  // P = agg16
    matmul_stats_kernel<16, 32, 16><<<NB_STATS, 256, 0, stream>>>(P, W2, b2, H, part_s, part_q);
    bn_finalize_kernel<<<32, 256, 0, stream>>>(part_s, part_q, bn_mean, bn_rstd);
    bn_relu_kernel<32, true><<<cdiv((long long)N_NODES * 32, BS), BS, 0, stream>>>(
        H, bn_mean, bn_rstd, g2, be2, dis, P);  // P = h2 * dis

    // ---- layer 3: gather at F=32, then 32->64 matmul
    gather_kernel<32><<<cdiv((long long)cdiv(N_NODES, 2) * 64, BS), BS, 0, stream>>>(
        row_ptr, deg_i, sorted_row, dis, P, H);  // H = agg32
    matmul_stats_kernel<32, 64, 32><<<NB_STATS, 256, 0, stream>>>(H, W3, b3, P, part_s, part_q);
    bn_finalize_kernel<<<64, 256, 0, stream>>>(part_s, part_q, bn_mean, bn_rstd);
    bn_relu_kernel<64, false><<<cdiv((long long)N_NODES * 64, BS), BS, 0, stream>>>(
        P, bn_mean, bn_rstd, g3, be3, dis, H);  // H = h3

    // ---- pool + fc
    hipMemsetAsync(pooled, 0, (64 * 64 + 64) * sizeof(float), stream);
    pool_kernel<<<cdiv(N_NODES, POOL_CHUNK), 64, 0, stream>>>(H, batch, pooled, cnt);
    final_kernel<<<1, B_GRAPHS * 10, 0, stream>>>(pooled, cnt, fcW, fcb, out);
}

// Round 9
// 337.403 us; speedup vs baseline: 10.2938x; 1.1713x over previous
//
#include <hip/hip_runtime.h>

#define N_NODES 100000
#define N_EDGES 1600000
#define B_GRAPHS 64
#define BN_EPS 1e-5
#define NB_STATS 1024 // blocks for matmul+stats kernels

#define NBUCK 256
#define BUCK_NODES 392   // 256*392 = 100352 >= N_NODES
#define PART_CHUNK 4096
#define NB_PART 391      // cdiv(N_EDGES, PART_CHUNK)

static inline int cdiv(long long a, int b) { return (int)((a + b - 1) / b); }

// ---------------- phase 1: bucket histogram of col ----------------
__global__ void part_hist_kernel(const int* __restrict__ col, int* __restrict__ bucket_cnt) {
    __shared__ int h[NBUCK];
    for (int i = threadIdx.x; i < NBUCK; i += 256) h[i] = 0;
    __syncthreads();
    long long ebase = (long long)blockIdx.x * PART_CHUNK;
    int n = (N_EDGES - ebase < PART_CHUNK) ? (int)(N_EDGES - ebase) : PART_CHUNK;
    for (int i = threadIdx.x; i < n; i += 256)
        atomicAdd(&h[col[ebase + i] / BUCK_NODES], 1);
    __syncthreads();
    for (int i = threadIdx.x; i < NBUCK; i += 256)
        if (h[i]) atomicAdd(&bucket_cnt[i], h[i]);
}

// ---------------- phase 2: scan bucket counts -> base & cursor ----------------
__global__ void part_scan_kernel(const int* __restrict__ bucket_cnt, int* __restrict__ bucket_base,
                                 int* __restrict__ bucket_cur) {
    __shared__ int s[NBUCK];
    int t = threadIdx.x;
    int v = bucket_cnt[t];
    s[t] = v;
    __syncthreads();
    for (int off = 1; off < NBUCK; off <<= 1) {
        int u = (t >= off) ? s[t - off] : 0;
        __syncthreads();
        s[t] += u;
        __syncthreads();
    }
    bucket_base[t] = s[t] - v;  // exclusive
    bucket_cur[t] = s[t] - v;
}

// ---------------- phase 3: partition edges into bucket-contiguous (row,col) pairs ----------------
__global__ void part_scatter_kernel(const int* __restrict__ row, const int* __restrict__ col,
                                    int* __restrict__ bucket_cur, int2* __restrict__ part_edges) {
    __shared__ int h[NBUCK];
    __shared__ int base_s[NBUCK];
    __shared__ int cur_s[NBUCK];
    long long ebase = (long long)blockIdx.x * PART_CHUNK;
    int n = (N_EDGES - ebase < PART_CHUNK) ? (int)(N_EDGES - ebase) : PART_CHUNK;
    for (int i = threadIdx.x; i < NBUCK; i += 256) h[i] = 0;
    __syncthreads();
    for (int i = threadIdx.x; i < n; i += 256)
        atomicAdd(&h[col[ebase + i] / BUCK_NODES], 1);
    __syncthreads();
    for (int i = threadIdx.x; i < NBUCK; i += 256) {
        int c = h[i];
        base_s[i] = c ? atomicAdd(&bucket_cur[i], c) : 0;
        cur_s[i] = 0;
    }
    __syncthreads();
    for (int i = threadIdx.x; i < n; i += 256) {
        int r = row[ebase + i], c = col[ebase + i];
        int bkt = c / BUCK_NODES;
        int p = base_s[bkt] + atomicAdd(&cur_s[bkt], 1);
        part_edges[p] = make_int2(r, c);
    }
}

// ---------------- phase 4: per-bucket CSR build (one block owns one bucket) ----------------
__global__ void csr_build_kernel(const int* __restrict__ bucket_base, const int2* __restrict__ part_edges,
                                 int* __restrict__ row_ptr, int* __restrict__ deg,
                                 float* __restrict__ dis, int* __restrict__ sorted_row) {
    __shared__ int hist[BUCK_NODES];  // histogram, then reused as scatter cursors
    __shared__ int tsum[256];
    int b = blockIdx.x;
    int t = threadIdx.x;
    int nbase = b * BUCK_NODES;
    int ebase = bucket_base[b];
    int eend = (b == NBUCK - 1) ? N_EDGES : bucket_base[b + 1];
    int ne = eend - ebase;
    for (int i = t; i < BUCK_NODES; i += 256) hist[i] = 0;
    __syncthreads();
    for (int i = t; i < ne; i += 256)
        atomicAdd(&hist[part_edges[ebase + i].y - nbase], 1);
    __syncthreads();
    int a0 = 0, a1 = 0;
    if (t < BUCK_NODES / 2) { a0 = hist[2 * t]; a1 = hist[2 * t + 1]; tsum[t] = a0 + a1; }
    else tsum[t] = 0;
    __syncthreads();
    for (int off = 1; off < 256; off <<= 1) {
        int u = (t >= off) ? tsum[t - off] : 0;
        __syncthreads();
        tsum[t] += u;
        __syncthreads();
    }
    if (t < BUCK_NODES / 2) {
        int excl = tsum[t] - (a0 + a1);
        hist[2 * t] = excl;
        hist[2 * t + 1] = excl + a0;
        int n0 = nbase + 2 * t, n1 = n0 + 1;
        if (n0 < N_NODES) {
            row_ptr[n0] = ebase + excl;
            deg[n0] = a0;
            dis[n0] = rsqrtf((float)a0 + 1.0f);
        }
        if (n1 < N_NODES) {
            row_ptr[n1] = ebase + excl + a0;
            deg[n1] = a1;
            dis[n1] = rsqrtf((float)a1 + 1.0f);
        }
    }
    __syncthreads();
    for (int i = t; i < ne; i += 256) {
        int2 e = part_edges[ebase + i];
        int p = atomicAdd(&hist[e.y - nbase], 1);
        sorted_row[ebase + p] = e.x;
    }
}

// ---------------- pre-scale x by dis, pad 3 -> 4 ----------------
__global__ void scale_x_kernel(const float* __restrict__ x, const float* __restrict__ dis,
                               float* __restrict__ xs4) {
    int i = blockIdx.x * blockDim.x + threadIdx.x;
    if (i < N_NODES) {
        float d = dis[i];
        xs4[i * 4 + 0] = x[i * 3 + 0] * d;
        xs4[i * 4 + 1] = x[i * 3 + 1] * d;
        xs4[i * 4 + 2] = x[i * 3 + 2] * d;
        xs4[i * 4 + 3] = 0.f;
    }
}

// ---------------- CSR gather at width F ----------------
template <int F>
__global__ void gather_kernel(const int* __restrict__ row_ptr, const int* __restrict__ deg,
                              const int* __restrict__ sorted_row, const float* __restrict__ dis,
                              const float* __restrict__ hs, float* __restrict__ agg) {
    const int NPW = 64 / F;
    int wave = (blockIdx.x * blockDim.x + threadIdx.x) >> 6;
    int lane = threadIdx.x & 63;
    int n = wave * NPW + lane / F;
    int f = lane % F;
    if (n >= N_NODES) return;
    int start = row_ptr[n];
    int d = deg[n];
    const int* sr = sorted_row + start;
    float acc = hs[(long long)n * F + f];  // self-loop term
    int j = 0;
    for (; j + 4 <= d; j += 4) {
        int r0 = sr[j], r1 = sr[j + 1], r2 = sr[j + 2], r3 = sr[j + 3];
        float a0 = hs[(long long)r0 * F + f];
        float a1 = hs[(long long)r1 * F + f];
        float a2 = hs[(long long)r2 * F + f];
        float a3 = hs[(long long)r3 * F + f];
        acc += (a0 + a1) + (a2 + a3);
    }
    for (; j < d; j++) acc += hs[(long long)sr[j] * F + f];
    agg[(long long)n * F + f] = dis[n] * acc;
}

// ---------------- matmul + bias + deterministic fp64 BN partials (transposed layout) ----------------
template <int IN, int OUT, int INSTRIDE>
__global__ void matmul_stats_kernel(const float* __restrict__ agg, const float* __restrict__ W,
                                    const float* __restrict__ b, float* __restrict__ pre,
                                    double* __restrict__ part_s, double* __restrict__ part_q) {
    __shared__ float Ws[IN * OUT];
    __shared__ double s_s[256];
    __shared__ double s_q[256];
    for (int k = threadIdx.x; k < IN * OUT; k += blockDim.x) Ws[k] = W[k];
    __syncthreads();
    const long long total = (long long)N_NODES * OUT;
    const long long stride = (long long)NB_STATS * 256;  // multiple of OUT
    long long t0 = (long long)blockIdx.x * 256 + threadIdx.x;
    int o = (int)(t0 % OUT);
    float bo = b[o];
    double my_s = 0.0, my_q = 0.0;
    for (long long t = t0; t < total; t += stride) {
        long long i = t / OUT;
        float acc = bo;
#pragma unroll
        for (int k = 0; k < IN; k++) acc += agg[i * INSTRIDE + k] * Ws[k * OUT + o];
        pre[t] = acc;
        my_s += (double)acc;
        my_q += (double)acc * (double)acc;
    }
    s_s[threadIdx.x] = my_s;
    s_q[threadIdx.x] = my_q;
    __syncthreads();
    if (threadIdx.x < OUT) {
        double ts = 0.0, tq = 0.0;
        for (int k = threadIdx.x; k < 256; k += OUT) { ts += s_s[k]; tq += s_q[k]; }
        part_s[(long long)threadIdx.x * NB_STATS + blockIdx.x] = ts;
        part_q[(long long)threadIdx.x * NB_STATS + blockIdx.x] = tq;
    }
}

// ---------------- finalize BN stats: one block per feature ----------------
__global__ void bn_finalize_kernel(const double* __restrict__ part_s, const double* __restrict__ part_q,
                                   float* __restrict__ bn_mean, float* __restrict__ bn_rstd) {
    __shared__ double s_s[256];
    __shared__ double s_q[256];
    int o = blockIdx.x;
    int t = threadIdx.x;
    double ms = 0.0, mq = 0.0;
#pragma unroll
    for (int k = 0; k < NB_STATS / 256; k++) {
        ms += part_s[(long long)o * NB_STATS + k * 256 + t];
        mq += part_q[(long long)o * NB_STATS + k * 256 + t];
    }
    s_s[t] = ms;
    s_q[t] = mq;
    __syncthreads();
    for (int off = 128; off > 0; off >>= 1) {
        if (t < off) { s_s[t] += s_s[t + off]; s_q[t] += s_q[t + off]; }
        __syncthreads();
    }
    if (t == 0) {
        double mean = s_s[0] / (double)N_NODES;
        double var = s_q[0] / (double)N_NODES - mean * mean;
        bn_mean[o] = (float)mean;
        bn_rstd[o] = (float)(1.0 / sqrt(var + BN_EPS));
    }
}

// ---------------- BN apply + ReLU (optionally pre-scale by dis for the next gather) ----------------
template <int F, bool SCALE>
__global__ void bn_relu_kernel(const float* __restrict__ pre, const float* __restrict__ bn_mean,
                               const float* __restrict__ bn_rstd, const float* __restrict__ g,
                               const float* __restrict__ be, const float* __restrict__ dis,
                               float* __restrict__ out) {
    int t = blockIdx.x * blockDim.x + threadIdx.x;
    const int total = N_NODES * F;
    if (t >= total) return;
    int f = t % F;
    float y = (pre[t] - bn_mean[f]) * bn_rstd[f] * g[f] + be[f];
    y = y > 0.f ? y : 0.f;
    if (SCALE) y *= dis[t / F];
    out[t] = y;
}

// ---------------- mean pool: one wave per 32-node chunk, lane = feature, 4x unrolled ----------------
// batch is SORTED -> register-accumulate, flush one atomic per graph boundary.
#define POOL_CHUNK 32
__global__ void pool_kernel(const float* __restrict__ h, const int* __restrict__ batch,
                            float* __restrict__ pooled, float* __restrict__ cnt) {
    int wave = (blockIdx.x * blockDim.x + threadIdx.x) >> 6;
    int lane = threadIdx.x & 63;  // feature index
    int start = wave * POOL_CHUNK;
    if (start >= N_NODES) return;
    int end = start + POOL_CHUNK;
    if (end > N_NODES) end = N_NODES;
    int cur = batch[start];  // wave-uniform -> scalar load
    float acc = 0.f;
    float c = 0.f;
    int i = start;
    for (; i + 4 <= end; i += 4) {
        // 4 independent loads issued together (MLP); batch ids are wave-uniform scalars
        int b0 = batch[i], b1 = batch[i + 1], b2 = batch[i + 2], b3 = batch[i + 3];
        float v0 = h[(long long)i * 64 + lane];
        float v1 = h[(long long)(i + 1) * 64 + lane];
        float v2 = h[(long long)(i + 2) * 64 + lane];
        float v3 = h[(long long)(i + 3) * 64 + lane];
        if (b0 != cur) { atomicAdd(&pooled[cur * 64 + lane], acc); if (lane == 0) atomicAdd(&cnt[cur], c); acc = 0.f; c = 0.f; cur = b0; }
        acc += v0; c += 1.f;
        if (b1 != cur) { atomicAdd(&pooled[cur * 64 + lane], acc); if (lane == 0) atomicAdd(&cnt[cur], c); acc = 0.f; c = 0.f; cur = b1; }
        acc += v1; c += 1.f;
        if (b2 != cur) { atomicAdd(&pooled[cur * 64 + lane], acc); if (lane == 0) atomicAdd(&cnt[cur], c); acc = 0.f; c = 0.f; cur = b2; }
        acc += v2; c += 1.f;
        if (b3 != cur) { atomicAdd(&pooled[cur * 64 + lane], acc); if (lane == 0) atomicAdd(&cnt[cur], c); acc = 0.f; c = 0.f; cur = b3; }
        acc += v3; c += 1.f;
    }
    for (; i < end; i++) {
        int b = batch[i];
        if (b != cur) { atomicAdd(&pooled[cur * 64 + lane], acc); if (lane == 0) atomicAdd(&cnt[cur], c); acc = 0.f; c = 0.f; cur = b; }
        acc += h[(long long)i * 64 + lane]; c += 1.f;
    }
    atomicAdd(&pooled[cur * 64 + lane], acc);
    if (lane == 0) atomicAdd(&cnt[cur], c);
}

// ---------------- final linear ----------------
__global__ void final_kernel(const float* __restrict__ pooled, const float* __restrict__ cnt,
                             const float* __restrict__ fcW, const float* __restrict__ fcb,
                             float* __restrict__ out) {
    int t = blockIdx.x * blockDim.x + threadIdx.x;
    if (t >= B_GRAPHS * 10) return;
    int b = t / 10, j = t % 10;
    float inv = 1.0f / fmaxf(cnt[b], 1.0f);
    float acc = fcb[j];
#pragma unroll
    for (int f = 0; f < 64; f++) acc += pooled[b * 64 + f] * inv * fcW[f * 10 + j];
    out[t] = acc;
}

extern "C" void kernel_launch(void* const* d_in, const int* in_sizes, int n_in,
                              void* d_out, int out_size, void* d_ws, size_t ws_size,
                              hipStream_t stream) {
    const float* x  = (const float*)d_in[0];
    const int* ei   = (const int*)d_in[1];
    const int* batch= (const int*)d_in[2];
    const float* W1 = (const float*)d_in[3];  const float* b1 = (const float*)d_in[4];
    const float* g1 = (const float*)d_in[5];  const float* be1= (const float*)d_in[6];
    const float* W2 = (const float*)d_in[7];  const float* b2 = (const float*)d_in[8];
    const float* g2 = (const float*)d_in[9];  const float* be2= (const float*)d_in[10];
    const float* W3 = (const float*)d_in[11]; const float* b3 = (const float*)d_in[12];
    const float* g3 = (const float*)d_in[13]; const float* be3= (const float*)d_in[14];
    const float* fcW= (const float*)d_in[15]; const float* fcb= (const float*)d_in[16];
    float* out = (float*)d_out;

    const int* row = ei;
    const int* col = ei + N_EDGES;

    // workspace layout
    char* wp = (char*)d_ws;
    float* dis        = (float*)wp;              wp += N_NODES * 4;
    int*   deg_i      = (int*)wp;                wp += N_NODES * 4;
    int*   row_ptr    = (int*)wp;                wp += N_NODES * 4;
    int*   bucket_cnt = (int*)wp;                wp += NBUCK * 4;
    int*   bucket_base= (int*)wp;                wp += NBUCK * 4;
    int*   bucket_cur = (int*)wp;                wp += NBUCK * 4;
    int*   sorted_row = (int*)wp;                wp += (size_t)N_EDGES * 4;
    int2*  part_edges = (int2*)wp;               wp += (size_t)N_EDGES * 8;
    double* part_s    = (double*)wp;             wp += (size_t)NB_STATS * 64 * 8;
    double* part_q    = (double*)wp;             wp += (size_t)NB_STATS * 64 * 8;
    float* bn_mean    = (float*)wp;              wp += 64 * 4;
    float* bn_rstd    = (float*)wp;              wp += 64 * 4;
    float* pooled     = (float*)wp;              wp += 64 * 64 * 4;
    float* cnt        = (float*)wp;              wp += 64 * 4;
    float* xs4        = (float*)wp;              wp += (size_t)N_NODES * 4 * 4;
    float* agg4       = (float*)wp;              wp += (size_t)N_NODES * 4 * 4;
    float* P          = (float*)wp;              wp += (size_t)N_NODES * 64 * 4;  // ping
    float* H          = (float*)wp;              wp += (size_t)N_NODES * 64 * 4;  // pong

    const int BS = 256;

    // ---- CSR build: bucketed two-phase (no cross-XCD scatter)
    hipMemsetAsync(bucket_cnt, 0, NBUCK * sizeof(int), stream);
    part_hist_kernel<<<NB_PART, 256, 0, stream>>>(col, bucket_cnt);
    part_scan_kernel<<<1, NBUCK, 0, stream>>>(bucket_cnt, bucket_base, bucket_cur);
    part_scatter_kernel<<<NB_PART, 256, 0, stream>>>(row, col, bucket_cur, part_edges);
    csr_build_kernel<<<NBUCK, 256, 0, stream>>>(bucket_base, part_edges, row_ptr, deg_i, dis, sorted_row);

    // ---- layer 1: gather at F=4 (x padded), then 3->16 matmul
    scale_x_kernel<<<cdiv(N_NODES, BS), BS, 0, stream>>>(x, dis, xs4);
    gather_kernel<4><<<cdiv((long long)cdiv(N_NODES, 16) * 64, BS), BS, 0, stream>>>(
        row_ptr, deg_i, sorted_row, dis, xs4, agg4);
    matmul_stats_kernel<3, 16, 4><<<NB_STATS, 256, 0, stream>>>(agg4, W1, b1, P, part_s, part_q);
    bn_finalize_kernel<<<16, 256, 0, stream>>>(part_s, part_q, bn_mean, bn_rstd);
    bn_relu_kernel<16, true><<<cdiv((long long)N_NODES * 16, BS), BS, 0, stream>>>(
        P, bn_mean, bn_rstd, g1, be1, dis, H);  // H = h1 * dis

    // ---- layer 2: gather at F=16, then 16->32 matmul
    gather_kernel<16><<<cdiv((long long)cdiv(N_NODES, 4) * 64, BS), BS, 0, stream>>>(
        row_ptr, deg_i, sorted_row, dis, H, P);  // P = agg16
    matmul_stats_kernel<16, 32, 16><<<NB_STATS, 256, 0, stream>>>(P, W2, b2, H, part_s, part_q);
    bn_finalize_kernel<<<32, 256, 0, stream>>>(part_s, part_q, bn_mean, bn_rstd);
    bn_relu_kernel<32, true><<<cdiv((long long)N_NODES * 32, BS), BS, 0, stream>>>(
        H, bn_mean, bn_rstd, g2, be2, dis, P);  // P = h2 * dis

    // ---- layer 3: gather at F=32, then 32->64 matmul
    gather_kernel<32><<<cdiv((long long)cdiv(N_NODES, 2) * 64, BS), BS, 0, stream>>>(
        row_ptr, deg_i, sorted_row, dis, P, H);  // H = agg32
    matmul_stats_kernel<32, 64, 32><<<NB_STATS, 256, 0, stream>>>(H, W3, b3, P, part_s, part_q);
    bn_finalize_kernel<<<64, 256, 0, stream>>>(part_s, part_q, bn_mean, bn_rstd);
    bn_relu_kernel<64, false><<<cdiv((long long)N_NODES * 64, BS), BS, 0, stream>>>(
        P, bn_mean, bn_rstd, g3, be3, dis, H);  // H = h3

    // ---- pool + fc
    hipMemsetAsync(pooled, 0, (64 * 64 + 64) * sizeof(float), stream);
    pool_kernel<<<cdiv((long long)cdiv(N_NODES, POOL_CHUNK) * 64, BS), BS, 0, stream>>>(H, batch, pooled, cnt);
    final_kernel<<<1, B_GRAPHS * 10, 0, stream>>>(pooled, cnt, fcW, fcb, out);
}

// Round 10
// 332.401 us; speedup vs baseline: 10.4487x; 1.0150x over previous
//
#include <hip/hip_runtime.h>

#define N_NODES 100000
#define N_EDGES 1600000
#define B_GRAPHS 64
#define BN_EPS 1e-5
#define NB_STATS 1024 // blocks for matmul+stats kernels

#define NBUCK 256
#define BUCK_NODES 392   // 256*392 = 100352 >= N_NODES; 392 < 512 -> 9-bit local id
#define PART_CHUNK 4096
#define NB_PART 391      // cdiv(N_EDGES, PART_CHUNK)

static inline int cdiv(long long a, int b) { return (int)((a + b - 1) / b); }

// ---------------- phase 1: bucket histogram of col ----------------
__global__ void part_hist_kernel(const int* __restrict__ col, int* __restrict__ bucket_cnt) {
    __shared__ int h[NBUCK];
    for (int i = threadIdx.x; i < NBUCK; i += 256) h[i] = 0;
    __syncthreads();
    long long ebase = (long long)blockIdx.x * PART_CHUNK;
    int n = (N_EDGES - ebase < PART_CHUNK) ? (int)(N_EDGES - ebase) : PART_CHUNK;
    for (int i = threadIdx.x; i < n; i += 256)
        atomicAdd(&h[col[ebase + i] / BUCK_NODES], 1);
    __syncthreads();
    for (int i = threadIdx.x; i < NBUCK; i += 256)
        if (h[i]) atomicAdd(&bucket_cnt[i], h[i]);
}

// ---------------- phase 2: scan bucket counts -> base & cursor ----------------
__global__ void part_scan_kernel(const int* __restrict__ bucket_cnt, int* __restrict__ bucket_base,
                                 int* __restrict__ bucket_cur) {
    __shared__ int s[NBUCK];
    int t = threadIdx.x;
    int v = bucket_cnt[t];
    s[t] = v;
    __syncthreads();
    for (int off = 1; off < NBUCK; off <<= 1) {
        int u = (t >= off) ? s[t - off] : 0;
        __syncthreads();
        s[t] += u;
        __syncthreads();
    }
    bucket_base[t] = s[t] - v;  // exclusive
    bucket_cur[t] = s[t] - v;
}

// ---------------- phase 3: partition edges; pack (row,local_col) into one uint ----------------
// row < 2^17, local col < 512 (9 bits) -> 26 bits total
__global__ void part_scatter_kernel(const int* __restrict__ row, const int* __restrict__ col,
                                    int* __restrict__ bucket_cur, unsigned* __restrict__ part_edges) {
    __shared__ int h[NBUCK];
    __shared__ int base_s[NBUCK];
    __shared__ int cur_s[NBUCK];
    long long ebase = (long long)blockIdx.x * PART_CHUNK;
    int n = (N_EDGES - ebase < PART_CHUNK) ? (int)(N_EDGES - ebase) : PART_CHUNK;
    for (int i = threadIdx.x; i < NBUCK; i += 256) h[i] = 0;
    __syncthreads();
    for (int i = threadIdx.x; i < n; i += 256)
        atomicAdd(&h[col[ebase + i] / BUCK_NODES], 1);
    __syncthreads();
    for (int i = threadIdx.x; i < NBUCK; i += 256) {
        int c = h[i];
        base_s[i] = c ? atomicAdd(&bucket_cur[i], c) : 0;
        cur_s[i] = 0;
    }
    __syncthreads();
    for (int i = threadIdx.x; i < n; i += 256) {
        int r = row[ebase + i], c = col[ebase + i];
        int bkt = c / BUCK_NODES;
        int p = base_s[bkt] + atomicAdd(&cur_s[bkt], 1);
        part_edges[p] = ((unsigned)r << 9) | (unsigned)(c - bkt * BUCK_NODES);
    }
}

// ---------------- phase 4: per-bucket CSR build (one block owns one bucket) ----------------
__global__ void csr_build_kernel(const int* __restrict__ bucket_base, const unsigned* __restrict__ part_edges,
                                 int* __restrict__ row_ptr, int* __restrict__ deg,
                                 float* __restrict__ dis, int* __restrict__ sorted_row) {
    __shared__ int hist[BUCK_NODES];  // histogram, then reused as scatter cursors
    __shared__ int tsum[256];
    int b = blockIdx.x;
    int t = threadIdx.x;
    int nbase = b * BUCK_NODES;
    int ebase = bucket_base[b];
    int eend = (b == NBUCK - 1) ? N_EDGES : bucket_base[b + 1];
    int ne = eend - ebase;
    for (int i = t; i < BUCK_NODES; i += 256) hist[i] = 0;
    __syncthreads();
    for (int i = t; i < ne; i += 256)
        atomicAdd(&hist[part_edges[ebase + i] & 511u], 1);
    __syncthreads();
    int a0 = 0, a1 = 0;
    if (t < BUCK_NODES / 2) { a0 = hist[2 * t]; a1 = hist[2 * t + 1]; tsum[t] = a0 + a1; }
    else tsum[t] = 0;
    __syncthreads();
    for (int off = 1; off < 256; off <<= 1) {
        int u = (t >= off) ? tsum[t - off] : 0;
        __syncthreads();
        tsum[t] += u;
        __syncthreads();
    }
    if (t < BUCK_NODES / 2) {
        int excl = tsum[t] - (a0 + a1);
        hist[2 * t] = excl;
        hist[2 * t + 1] = excl + a0;
        int n0 = nbase + 2 * t, n1 = n0 + 1;
        if (n0 < N_NODES) {
            row_ptr[n0] = ebase + excl;
            deg[n0] = a0;
            dis[n0] = rsqrtf((float)a0 + 1.0f);
        }
        if (n1 < N_NODES) {
            row_ptr[n1] = ebase + excl + a0;
            deg[n1] = a1;
            dis[n1] = rsqrtf((float)a1 + 1.0f);
        }
    }
    __syncthreads();
    for (int i = t; i < ne; i += 256) {
        unsigned e = part_edges[ebase + i];
        int p = atomicAdd(&hist[e & 511u], 1);
        sorted_row[ebase + p] = (int)(e >> 9);
    }
}

// ---------------- pre-scale x by dis, pad 3 -> 4, store fp16 ----------------
__global__ void scale_x_kernel(const float* __restrict__ x, const float* __restrict__ dis,
                               _Float16* __restrict__ xs4) {
    int i = blockIdx.x * blockDim.x + threadIdx.x;
    if (i < N_NODES) {
        float d = dis[i];
        xs4[i * 4 + 0] = (_Float16)(x[i * 3 + 0] * d);
        xs4[i * 4 + 1] = (_Float16)(x[i * 3 + 1] * d);
        xs4[i * 4 + 2] = (_Float16)(x[i * 3 + 2] * d);
        xs4[i * 4 + 3] = (_Float16)0.f;
    }
}

// ---------------- CSR gather at width F (fp16 source, fp32 accumulate) ----------------
template <int F>
__global__ void gather_kernel(const int* __restrict__ row_ptr, const int* __restrict__ deg,
                              const int* __restrict__ sorted_row, const float* __restrict__ dis,
                              const _Float16* __restrict__ hs, float* __restrict__ agg) {
    const int NPW = 64 / F;
    int wave = (blockIdx.x * blockDim.x + threadIdx.x) >> 6;
    int lane = threadIdx.x & 63;
    int n = wave * NPW + lane / F;
    int f = lane % F;
    if (n >= N_NODES) return;
    int start = row_ptr[n];
    int d = deg[n];
    const int* sr = sorted_row + start;
    float acc = (float)hs[(long long)n * F + f];  // self-loop term
    int j = 0;
    for (; j + 4 <= d; j += 4) {
        int r0 = sr[j], r1 = sr[j + 1], r2 = sr[j + 2], r3 = sr[j + 3];
        float a0 = (float)hs[(long long)r0 * F + f];
        float a1 = (float)hs[(long long)r1 * F + f];
        float a2 = (float)hs[(long long)r2 * F + f];
        float a3 = (float)hs[(long long)r3 * F + f];
        acc += (a0 + a1) + (a2 + a3);
    }
    for (; j < d; j++) acc += (float)hs[(long long)sr[j] * F + f];
    agg[(long long)n * F + f] = dis[n] * acc;
}

// ---------------- matmul + bias + deterministic fp64 BN partials (transposed layout) ----------------
template <int IN, int OUT, int INSTRIDE>
__global__ void matmul_stats_kernel(const float* __restrict__ agg, const float* __restrict__ W,
                                    const float* __restrict__ b, float* __restrict__ pre,
                                    double* __restrict__ part_s, double* __restrict__ part_q) {
    __shared__ float Ws[IN * OUT];
    __shared__ double s_s[256];
    __shared__ double s_q[256];
    for (int k = threadIdx.x; k < IN * OUT; k += blockDim.x) Ws[k] = W[k];
    __syncthreads();
    const long long total = (long long)N_NODES * OUT;
    const long long stride = (long long)NB_STATS * 256;  // multiple of OUT
    long long t0 = (long long)blockIdx.x * 256 + threadIdx.x;
    int o = (int)(t0 % OUT);
    float bo = b[o];
    double my_s = 0.0, my_q = 0.0;
    for (long long t = t0; t < total; t += stride) {
        long long i = t / OUT;
        float acc = bo;
#pragma unroll
        for (int k = 0; k < IN; k++) acc += agg[i * INSTRIDE + k] * Ws[k * OUT + o];
        pre[t] = acc;
        my_s += (double)acc;
        my_q += (double)acc * (double)acc;
    }
    s_s[threadIdx.x] = my_s;
    s_q[threadIdx.x] = my_q;
    __syncthreads();
    if (threadIdx.x < OUT) {
        double ts = 0.0, tq = 0.0;
        for (int k = threadIdx.x; k < 256; k += OUT) { ts += s_s[k]; tq += s_q[k]; }
        part_s[(long long)threadIdx.x * NB_STATS + blockIdx.x] = ts;
        part_q[(long long)threadIdx.x * NB_STATS + blockIdx.x] = tq;
    }
}

// ---------------- finalize BN stats: one block per feature ----------------
__global__ void bn_finalize_kernel(const double* __restrict__ part_s, const double* __restrict__ part_q,
                                   float* __restrict__ bn_mean, float* __restrict__ bn_rstd) {
    __shared__ double s_s[256];
    __shared__ double s_q[256];
    int o = blockIdx.x;
    int t = threadIdx.x;
    double ms = 0.0, mq = 0.0;
#pragma unroll
    for (int k = 0; k < NB_STATS / 256; k++) {
        ms += part_s[(long long)o * NB_STATS + k * 256 + t];
        mq += part_q[(long long)o * NB_STATS + k * 256 + t];
    }
    s_s[t] = ms;
    s_q[t] = mq;
    __syncthreads();
    for (int off = 128; off > 0; off >>= 1) {
        if (t < off) { s_s[t] += s_s[t + off]; s_q[t] += s_q[t + off]; }
        __syncthreads();
    }
    if (t == 0) {
        double mean = s_s[0] / (double)N_NODES;
        double var = s_q[0] / (double)N_NODES - mean * mean;
        bn_mean[o] = (float)mean;
        bn_rstd[o] = (float)(1.0 / sqrt(var + BN_EPS));
    }
}

// ---------------- BN apply + ReLU; TOUT selects fp16 (next-gather input) or fp32 ----------------
template <int F, bool SCALE, typename TOUT>
__global__ void bn_relu_kernel(const float* __restrict__ pre, const float* __restrict__ bn_mean,
                               const float* __restrict__ bn_rstd, const float* __restrict__ g,
                               const float* __restrict__ be, const float* __restrict__ dis,
                               TOUT* __restrict__ out) {
    int t = blockIdx.x * blockDim.x + threadIdx.x;
    const int total = N_NODES * F;
    if (t >= total) return;
    int f = t % F;
    float y = (pre[t] - bn_mean[f]) * bn_rstd[f] * g[f] + be[f];
    y = y > 0.f ? y : 0.f;
    if (SCALE) y *= dis[t / F];
    out[t] = (TOUT)y;
}

// ---------------- mean pool: one wave per 32-node chunk, lane = feature, 4x unrolled ----------------
#define POOL_CHUNK 32
__global__ void pool_kernel(const float* __restrict__ h, const int* __restrict__ batch,
                            float* __restrict__ pooled, float* __restrict__ cnt) {
    int wave = (blockIdx.x * blockDim.x + threadIdx.x) >> 6;
    int lane = threadIdx.x & 63;  // feature index
    int start = wave * POOL_CHUNK;
    if (start >= N_NODES) return;
    int end = start + POOL_CHUNK;
    if (end > N_NODES) end = N_NODES;
    int cur = batch[start];  // wave-uniform -> scalar load
    float acc = 0.f;
    float c = 0.f;
    int i = start;
    for (; i + 4 <= end; i += 4) {
        int b0 = batch[i], b1 = batch[i + 1], b2 = batch[i + 2], b3 = batch[i + 3];
        float v0 = h[(long long)i * 64 + lane];
        float v1 = h[(long long)(i + 1) * 64 + lane];
        float v2 = h[(long long)(i + 2) * 64 + lane];
        float v3 = h[(long long)(i + 3) * 64 + lane];
        if (b0 != cur) { atomicAdd(&pooled[cur * 64 + lane], acc); if (lane == 0) atomicAdd(&cnt[cur], c); acc = 0.f; c = 0.f; cur = b0; }
        acc += v0; c += 1.f;
        if (b1 != cur) { atomicAdd(&pooled[cur * 64 + lane], acc); if (lane == 0) atomicAdd(&cnt[cur], c); acc = 0.f; c = 0.f; cur = b1; }
        acc += v1; c += 1.f;
        if (b2 != cur) { atomicAdd(&pooled[cur * 64 + lane], acc); if (lane == 0) atomicAdd(&cnt[cur], c); acc = 0.f; c = 0.f; cur = b2; }
        acc += v2; c += 1.f;
        if (b3 != cur) { atomicAdd(&pooled[cur * 64 + lane], acc); if (lane == 0) atomicAdd(&cnt[cur], c); acc = 0.f; c = 0.f; cur = b3; }
        acc += v3; c += 1.f;
    }
    for (; i < end; i++) {
        int b = batch[i];
        if (b != cur) { atomicAdd(&pooled[cur * 64 + lane], acc); if (lane == 0) atomicAdd(&cnt[cur], c); acc = 0.f; c = 0.f; cur = b; }
        acc += h[(long long)i * 64 + lane]; c += 1.f;
    }
    atomicAdd(&pooled[cur * 64 + lane], acc);
    if (lane == 0) atomicAdd(&cnt[cur], c);
}

// ---------------- final linear ----------------
__global__ void final_kernel(const float* __restrict__ pooled, const float* __restrict__ cnt,
                             const float* __restrict__ fcW, const float* __restrict__ fcb,
                             float* __restrict__ out) {
    int t = blockIdx.x * blockDim.x + threadIdx.x;
    if (t >= B_GRAPHS * 10) return;
    int b = t / 10, j = t % 10;
    float inv = 1.0f / fmaxf(cnt[b], 1.0f);
    float acc = fcb[j];
#pragma unroll
    for (int f = 0; f < 64; f++) acc += pooled[b * 64 + f] * inv * fcW[f * 10 + j];
    out[t] = acc;
}

extern "C" void kernel_launch(void* const* d_in, const int* in_sizes, int n_in,
                              void* d_out, int out_size, void* d_ws, size_t ws_size,
                              hipStream_t stream) {
    const float* x  = (const float*)d_in[0];
    const int* ei   = (const int*)d_in[1];
    const int* batch= (const int*)d_in[2];
    const float* W1 = (const float*)d_in[3];  const float* b1 = (const float*)d_in[4];
    const float* g1 = (const float*)d_in[5];  const float* be1= (const float*)d_in[6];
    const float* W2 = (const float*)d_in[7];  const float* b2 = (const float*)d_in[8];
    const float* g2 = (const float*)d_in[9];  const float* be2= (const float*)d_in[10];
    const float* W3 = (const float*)d_in[11]; const float* b3 = (const float*)d_in[12];
    const float* g3 = (const float*)d_in[13]; const float* be3= (const float*)d_in[14];
    const float* fcW= (const float*)d_in[15]; const float* fcb= (const float*)d_in[16];
    float* out = (float*)d_out;

    const int* row = ei;
    const int* col = ei + N_EDGES;

    // workspace layout (all blocks 256B-aligned by construction order)
    char* wp = (char*)d_ws;
    float* dis        = (float*)wp;              wp += N_NODES * 4;
    int*   deg_i      = (int*)wp;                wp += N_NODES * 4;
    int*   row_ptr    = (int*)wp;                wp += N_NODES * 4;
    int*   bucket_cnt = (int*)wp;                wp += NBUCK * 4;
    int*   bucket_base= (int*)wp;                wp += NBUCK * 4;
    int*   bucket_cur = (int*)wp;                wp += NBUCK * 4;
    int*   sorted_row = (int*)wp;                wp += (size_t)N_EDGES * 4;
    unsigned* part_edges = (unsigned*)wp;        wp += (size_t)N_EDGES * 4;
    double* part_s    = (double*)wp;             wp += (size_t)NB_STATS * 64 * 8;
    double* part_q    = (double*)wp;             wp += (size_t)NB_STATS * 64 * 8;
    float* bn_mean    = (float*)wp;              wp += 64 * 4;
    float* bn_rstd    = (float*)wp;              wp += 64 * 4;
    float* pooled     = (float*)wp;              wp += 64 * 64 * 4;
    float* cnt        = (float*)wp;              wp += 64 * 4;
    _Float16* xs4h    = (_Float16*)wp;           wp += (size_t)N_NODES * 4 * 2;
    float* agg4       = (float*)wp;              wp += (size_t)N_NODES * 4 * 4;
    float* AGG        = (float*)wp;              wp += (size_t)N_NODES * 32 * 4;  // gather out (fp32, <=N*32)
    float* PRE        = (float*)wp;              wp += (size_t)N_NODES * 64 * 4;  // matmul out (fp32, <=N*64)
    _Float16* Hh      = (_Float16*)wp;           wp += (size_t)N_NODES * 32 * 2;  // BN out for gathers (fp16)
    float* Hf         = (float*)wp;              wp += (size_t)N_NODES * 64 * 4;  // h3 (fp32) for pool

    const int BS = 256;

    // ---- CSR build: bucketed two-phase (no cross-XCD scatter)
    hipMemsetAsync(bucket_cnt, 0, NBUCK * sizeof(int), stream);
    part_hist_kernel<<<NB_PART, 256, 0, stream>>>(col, bucket_cnt);
    part_scan_kernel<<<1, NBUCK, 0, stream>>>(bucket_cnt, bucket_base, bucket_cur);
    part_scatter_kernel<<<NB_PART, 256, 0, stream>>>(row, col, bucket_cur, part_edges);
    csr_build_kernel<<<NBUCK, 256, 0, stream>>>(bucket_base, part_edges, row_ptr, deg_i, dis, sorted_row);

    // ---- layer 1: gather at F=4 (x padded, fp16), then 3->16 matmul
    scale_x_kernel<<<cdiv(N_NODES, BS), BS, 0, stream>>>(x, dis, xs4h);
    gather_kernel<4><<<cdiv((long long)cdiv(N_NODES, 16) * 64, BS), BS, 0, stream>>>(
        row_ptr, deg_i, sorted_row, dis, xs4h, agg4);
    matmul_stats_kernel<3, 16, 4><<<NB_STATS, 256, 0, stream>>>(agg4, W1, b1, PRE, part_s, part_q);
    bn_finalize_kernel<<<16, 256, 0, stream>>>(part_s, part_q, bn_mean, bn_rstd);
    bn_relu_kernel<16, true, _Float16><<<cdiv((long long)N_NODES * 16, BS), BS, 0, stream>>>(
        PRE, bn_mean, bn_rstd, g1, be1, dis, Hh);  // Hh = h1 * dis (fp16)

    // ---- layer 2: gather at F=16 (fp16), then 16->32 matmul
    gather_kernel<16><<<cdiv((long long)cdiv(N_NODES, 4) * 64, BS), BS, 0, stream>>>(
        row_ptr, deg_i, sorted_row, dis, Hh, AGG);
    matmul_stats_kernel<16, 32, 16><<<NB_STATS, 256, 0, stream>>>(AGG, W2, b2, PRE, part_s, part_q);
    bn_finalize_kernel<<<32, 256, 0, stream>>>(part_s, part_q, bn_mean, bn_rstd);
    bn_relu_kernel<32, true, _Float16><<<cdiv((long long)N_NODES * 32, BS), BS, 0, stream>>>(
        PRE, bn_mean, bn_rstd, g2, be2, dis, Hh);  // Hh = h2 * dis (fp16)

    // ---- layer 3: gather at F=32 (fp16), then 32->64 matmul
    gather_kernel<32><<<cdiv((long long)cdiv(N_NODES, 2) * 64, BS), BS, 0, stream>>>(
        row_ptr, deg_i, sorted_row, dis, Hh, AGG);
    matmul_stats_kernel<32, 64, 32><<<NB_STATS, 256, 0, stream>>>(AGG, W3, b3, PRE, part_s, part_q);
    bn_finalize_kernel<<<64, 256, 0, stream>>>(part_s, part_q, bn_mean, bn_rstd);
    bn_relu_kernel<64, false, float><<<cdiv((long long)N_NODES * 64, BS), BS, 0, stream>>>(
        PRE, bn_mean, bn_rstd, g3, be3, dis, Hf);  // Hf = h3 (fp32)

    // ---- pool + fc
    hipMemsetAsync(pooled, 0, (64 * 64 + 64) * sizeof(float), stream);
    pool_kernel<<<cdiv((long long)cdiv(N_NODES, POOL_CHUNK) * 64, BS), BS, 0, stream>>>(Hf, batch, pooled, cnt);
    final_kernel<<<1, B_GRAPHS * 10, 0, stream>>>(pooled, cnt, fcW, fcb, out);
}

// Round 11
// 309.055 us; speedup vs baseline: 11.2380x; 1.0755x over previous
//
#include <hip/hip_runtime.h>

#define N_NODES 100000
#define N_EDGES 1600000
#define B_GRAPHS 64
#define BN_EPS 1e-5
#define NB_STATS 1024 // blocks for matmul+stats kernels

#define NBUCK 256
#define BUCK_NODES 392   // 256*392 = 100352 >= N_NODES; 392 < 512 -> 9-bit local id
#define PART_CHUNK 4096
#define NB_PART 391      // cdiv(N_EDGES, PART_CHUNK)

typedef _Float16 f16x2 __attribute__((ext_vector_type(2)));

static inline int cdiv(long long a, int b) { return (int)((a + b - 1) / b); }

// ---------------- phase 1: bucket histogram of col ----------------
__global__ void part_hist_kernel(const int* __restrict__ col, int* __restrict__ bucket_cnt) {
    __shared__ int h[NBUCK];
    for (int i = threadIdx.x; i < NBUCK; i += 256) h[i] = 0;
    __syncthreads();
    long long ebase = (long long)blockIdx.x * PART_CHUNK;
    int n = (N_EDGES - ebase < PART_CHUNK) ? (int)(N_EDGES - ebase) : PART_CHUNK;
    for (int i = threadIdx.x; i < n; i += 256)
        atomicAdd(&h[col[ebase + i] / BUCK_NODES], 1);
    __syncthreads();
    for (int i = threadIdx.x; i < NBUCK; i += 256)
        if (h[i]) atomicAdd(&bucket_cnt[i], h[i]);
}

// ---------------- phase 2: scan bucket counts -> base & cursor ----------------
__global__ void part_scan_kernel(const int* __restrict__ bucket_cnt, int* __restrict__ bucket_base,
                                 int* __restrict__ bucket_cur) {
    __shared__ int s[NBUCK];
    int t = threadIdx.x;
    int v = bucket_cnt[t];
    s[t] = v;
    __syncthreads();
    for (int off = 1; off < NBUCK; off <<= 1) {
        int u = (t >= off) ? s[t - off] : 0;
        __syncthreads();
        s[t] += u;
        __syncthreads();
    }
    bucket_base[t] = s[t] - v;  // exclusive
    bucket_cur[t] = s[t] - v;
}

// ---------------- phase 3: partition edges; pack (row,local_col) into one uint ----------------
__global__ void part_scatter_kernel(const int* __restrict__ row, const int* __restrict__ col,
                                    int* __restrict__ bucket_cur, unsigned* __restrict__ part_edges) {
    __shared__ int h[NBUCK];
    __shared__ int base_s[NBUCK];
    __shared__ int cur_s[NBUCK];
    long long ebase = (long long)blockIdx.x * PART_CHUNK;
    int n = (N_EDGES - ebase < PART_CHUNK) ? (int)(N_EDGES - ebase) : PART_CHUNK;
    for (int i = threadIdx.x; i < NBUCK; i += 256) h[i] = 0;
    __syncthreads();
    for (int i = threadIdx.x; i < n; i += 256)
        atomicAdd(&h[col[ebase + i] / BUCK_NODES], 1);
    __syncthreads();
    for (int i = threadIdx.x; i < NBUCK; i += 256) {
        int c = h[i];
        base_s[i] = c ? atomicAdd(&bucket_cur[i], c) : 0;
        cur_s[i] = 0;
    }
    __syncthreads();
    for (int i = threadIdx.x; i < n; i += 256) {
        int r = row[ebase + i], c = col[ebase + i];
        int bkt = c / BUCK_NODES;
        int p = base_s[bkt] + atomicAdd(&cur_s[bkt], 1);
        part_edges[p] = ((unsigned)r << 9) | (unsigned)(c - bkt * BUCK_NODES);
    }
}

// ---------------- phase 4: per-bucket CSR build (one block owns one bucket) ----------------
__global__ void csr_build_kernel(const int* __restrict__ bucket_base, const unsigned* __restrict__ part_edges,
                                 int* __restrict__ row_ptr, int* __restrict__ deg,
                                 float* __restrict__ dis, int* __restrict__ sorted_row) {
    __shared__ int hist[BUCK_NODES];  // histogram, then reused as scatter cursors
    __shared__ int tsum[256];
    int b = blockIdx.x;
    int t = threadIdx.x;
    int nbase = b * BUCK_NODES;
    int ebase = bucket_base[b];
    int eend = (b == NBUCK - 1) ? N_EDGES : bucket_base[b + 1];
    int ne = eend - ebase;
    for (int i = t; i < BUCK_NODES; i += 256) hist[i] = 0;
    __syncthreads();
    for (int i = t; i < ne; i += 256)
        atomicAdd(&hist[part_edges[ebase + i] & 511u], 1);
    __syncthreads();
    int a0 = 0, a1 = 0;
    if (t < BUCK_NODES / 2) { a0 = hist[2 * t]; a1 = hist[2 * t + 1]; tsum[t] = a0 + a1; }
    else tsum[t] = 0;
    __syncthreads();
    for (int off = 1; off < 256; off <<= 1) {
        int u = (t >= off) ? tsum[t - off] : 0;
        __syncthreads();
        tsum[t] += u;
        __syncthreads();
    }
    if (t < BUCK_NODES / 2) {
        int excl = tsum[t] - (a0 + a1);
        hist[2 * t] = excl;
        hist[2 * t + 1] = excl + a0;
        int n0 = nbase + 2 * t, n1 = n0 + 1;
        if (n0 < N_NODES) {
            row_ptr[n0] = ebase + excl;
            deg[n0] = a0;
            dis[n0] = rsqrtf((float)a0 + 1.0f);
        }
        if (n1 < N_NODES) {
            row_ptr[n1] = ebase + excl + a0;
            deg[n1] = a1;
            dis[n1] = rsqrtf((float)a1 + 1.0f);
        }
    }
    __syncthreads();
    for (int i = t; i < ne; i += 256) {
        unsigned e = part_edges[ebase + i];
        int p = atomicAdd(&hist[e & 511u], 1);
        sorted_row[ebase + p] = (int)(e >> 9);
    }
}

// ---------------- pre-scale x by dis, pad 3 -> 4, store fp16 ----------------
__global__ void scale_x_kernel(const float* __restrict__ x, const float* __restrict__ dis,
                               _Float16* __restrict__ xs4) {
    int i = blockIdx.x * blockDim.x + threadIdx.x;
    if (i < N_NODES) {
        float d = dis[i];
        xs4[i * 4 + 0] = (_Float16)(x[i * 3 + 0] * d);
        xs4[i * 4 + 1] = (_Float16)(x[i * 3 + 1] * d);
        xs4[i * 4 + 2] = (_Float16)(x[i * 3 + 2] * d);
        xs4[i * 4 + 3] = (_Float16)0.f;
    }
}

// ---------------- CSR gather at width F: each lane handles a FEATURE PAIR via f16x2 ----------------
// F/2 lanes per node -> 128/F nodes per wave; halves vmem instruction count vs scalar fp16.
template <int F>
__global__ void gather_kernel(const int* __restrict__ row_ptr, const int* __restrict__ deg,
                              const int* __restrict__ sorted_row, const float* __restrict__ dis,
                              const _Float16* __restrict__ hs, float* __restrict__ agg) {
    const int LPN = F / 2;        // lanes per node
    const int NPW = 64 / LPN;     // nodes per wave
    int wave = (blockIdx.x * blockDim.x + threadIdx.x) >> 6;
    int lane = threadIdx.x & 63;
    int n = wave * NPW + lane / LPN;
    int p = lane % LPN;           // feature-pair index
    if (n >= N_NODES) return;
    int start = row_ptr[n];
    int d = deg[n];
    const int* sr = sorted_row + start;
    const f16x2* h2 = (const f16x2*)hs;
    f16x2 v = h2[(long long)n * LPN + p];  // self-loop term
    float acc0 = (float)v.x, acc1 = (float)v.y;
    int j = 0;
    for (; j + 4 <= d; j += 4) {
        int r0 = sr[j], r1 = sr[j + 1], r2 = sr[j + 2], r3 = sr[j + 3];
        f16x2 a0 = h2[(long long)r0 * LPN + p];
        f16x2 a1 = h2[(long long)r1 * LPN + p];
        f16x2 a2 = h2[(long long)r2 * LPN + p];
        f16x2 a3 = h2[(long long)r3 * LPN + p];
        acc0 += ((float)a0.x + (float)a1.x) + ((float)a2.x + (float)a3.x);
        acc1 += ((float)a0.y + (float)a1.y) + ((float)a2.y + (float)a3.y);
    }
    for (; j < d; j++) {
        f16x2 a = h2[(long long)sr[j] * LPN + p];
        acc0 += (float)a.x;
        acc1 += (float)a.y;
    }
    float dn = dis[n];
    float2 o;
    o.x = dn * acc0;
    o.y = dn * acc1;
    ((float2*)agg)[(long long)n * LPN + p] = o;
}

// ---------------- matmul + bias -> fp16 pre + deterministic fp64 BN partials on QUANTIZED values ----------------
template <int IN, int OUT, int INSTRIDE>
__global__ void matmul_stats_kernel(const float* __restrict__ agg, const float* __restrict__ W,
                                    const float* __restrict__ b, _Float16* __restrict__ pre,
                                    double* __restrict__ part_s, double* __restrict__ part_q) {
    __shared__ float Ws[IN * OUT];
    __shared__ double s_s[256];
    __shared__ double s_q[256];
    for (int k = threadIdx.x; k < IN * OUT; k += blockDim.x) Ws[k] = W[k];
    __syncthreads();
    const long long total = (long long)N_NODES * OUT;
    const long long stride = (long long)NB_STATS * 256;  // multiple of OUT
    long long t0 = (long long)blockIdx.x * 256 + threadIdx.x;
    int o = (int)(t0 % OUT);
    float bo = b[o];
    double my_s = 0.0, my_q = 0.0;
    for (long long t = t0; t < total; t += stride) {
        long long i = t / OUT;
        float acc = bo;
#pragma unroll
        for (int k = 0; k < IN; k++) acc += agg[i * INSTRIDE + k] * Ws[k * OUT + o];
        _Float16 q = (_Float16)acc;
        pre[t] = q;
        float fq = (float)q;  // stats on the quantized values -> self-consistent with bn_relu read
        my_s += (double)fq;
        my_q += (double)fq * (double)fq;
    }
    s_s[threadIdx.x] = my_s;
    s_q[threadIdx.x] = my_q;
    __syncthreads();
    if (threadIdx.x < OUT) {
        double ts = 0.0, tq = 0.0;
        for (int k = threadIdx.x; k < 256; k += OUT) { ts += s_s[k]; tq += s_q[k]; }
        part_s[(long long)threadIdx.x * NB_STATS + blockIdx.x] = ts;
        part_q[(long long)threadIdx.x * NB_STATS + blockIdx.x] = tq;
    }
}

// ---------------- finalize BN stats: one block per feature ----------------
__global__ void bn_finalize_kernel(const double* __restrict__ part_s, const double* __restrict__ part_q,
                                   float* __restrict__ bn_mean, float* __restrict__ bn_rstd) {
    __shared__ double s_s[256];
    __shared__ double s_q[256];
    int o = blockIdx.x;
    int t = threadIdx.x;
    double ms = 0.0, mq = 0.0;
#pragma unroll
    for (int k = 0; k < NB_STATS / 256; k++) {
        ms += part_s[(long long)o * NB_STATS + k * 256 + t];
        mq += part_q[(long long)o * NB_STATS + k * 256 + t];
    }
    s_s[t] = ms;
    s_q[t] = mq;
    __syncthreads();
    for (int off = 128; off > 0; off >>= 1) {
        if (t < off) { s_s[t] += s_s[t + off]; s_q[t] += s_q[t + off]; }
        __syncthreads();
    }
    if (t == 0) {
        double mean = s_s[0] / (double)N_NODES;
        double var = s_q[0] / (double)N_NODES - mean * mean;
        bn_mean[o] = (float)mean;
        bn_rstd[o] = (float)(1.0 / sqrt(var + BN_EPS));
    }
}

// ---------------- BN apply + ReLU; fp16 in, fp16 out ----------------
template <int F, bool SCALE>
__global__ void bn_relu_kernel(const _Float16* __restrict__ pre, const float* __restrict__ bn_mean,
                               const float* __restrict__ bn_rstd, const float* __restrict__ g,
                               const float* __restrict__ be, const float* __restrict__ dis,
                               _Float16* __restrict__ out) {
    int t = blockIdx.x * blockDim.x + threadIdx.x;
    const int total = N_NODES * F;
    if (t >= total) return;
    int f = t % F;
    float y = ((float)pre[t] - bn_mean[f]) * bn_rstd[f] * g[f] + be[f];
    y = y > 0.f ? y : 0.f;
    if (SCALE) y *= dis[t / F];
    out[t] = (_Float16)y;
}

// ---------------- mean pool (fp16 input): one wave per 32-node chunk, 4x unrolled ----------------
#define POOL_CHUNK 32
__global__ void pool_kernel(const _Float16* __restrict__ h, const int* __restrict__ batch,
                            float* __restrict__ pooled, float* __restrict__ cnt) {
    int wave = (blockIdx.x * blockDim.x + threadIdx.x) >> 6;
    int lane = threadIdx.x & 63;  // feature index
    int start = wave * POOL_CHUNK;
    if (start >= N_NODES) return;
    int end = start + POOL_CHUNK;
    if (end > N_NODES) end = N_NODES;
    int cur = batch[start];  // wave-uniform -> scalar load
    float acc = 0.f;
    float c = 0.f;
    int i = start;
    for (; i + 4 <= end; i += 4) {
        int b0 = batch[i], b1 = batch[i + 1], b2 = batch[i + 2], b3 = batch[i + 3];
        float v0 = (float)h[(long long)i * 64 + lane];
        float v1 = (float)h[(long long)(i + 1) * 64 + lane];
        float v2 = (float)h[(long long)(i + 2) * 64 + lane];
        float v3 = (float)h[(long long)(i + 3) * 64 + lane];
        if (b0 != cur) { atomicAdd(&pooled[cur * 64 + lane], acc); if (lane == 0) atomicAdd(&cnt[cur], c); acc = 0.f; c = 0.f; cur = b0; }
        acc += v0; c += 1.f;
        if (b1 != cur) { atomicAdd(&pooled[cur * 64 + lane], acc); if (lane == 0) atomicAdd(&cnt[cur], c); acc = 0.f; c = 0.f; cur = b1; }
        acc += v1; c += 1.f;
        if (b2 != cur) { atomicAdd(&pooled[cur * 64 + lane], acc); if (lane == 0) atomicAdd(&cnt[cur], c); acc = 0.f; c = 0.f; cur = b2; }
        acc += v2; c += 1.f;
        if (b3 != cur) { atomicAdd(&pooled[cur * 64 + lane], acc); if (lane == 0) atomicAdd(&cnt[cur], c); acc = 0.f; c = 0.f; cur = b3; }
        acc += v3; c += 1.f;
    }
    for (; i < end; i++) {
        int b = batch[i];
        if (b != cur) { atomicAdd(&pooled[cur * 64 + lane], acc); if (lane == 0) atomicAdd(&cnt[cur], c); acc = 0.f; c = 0.f; cur = b; }
        acc += (float)h[(long long)i * 64 + lane]; c += 1.f;
    }
    atomicAdd(&pooled[cur * 64 + lane], acc);
    if (lane == 0) atomicAdd(&cnt[cur], c);
}

// ---------------- final linear ----------------
__global__ void final_kernel(const float* __restrict__ pooled, const float* __restrict__ cnt,
                             const float* __restrict__ fcW, const float* __restrict__ fcb,
                             float* __restrict__ out) {
    int t = blockIdx.x * blockDim.x + threadIdx.x;
    if (t >= B_GRAPHS * 10) return;
    int b = t / 10, j = t % 10;
    float inv = 1.0f / fmaxf(cnt[b], 1.0f);
    float acc = fcb[j];
#pragma unroll
    for (int f = 0; f < 64; f++) acc += pooled[b * 64 + f] * inv * fcW[f * 10 + j];
    out[t] = acc;
}

extern "C" void kernel_launch(void* const* d_in, const int* in_sizes, int n_in,
                              void* d_out, int out_size, void* d_ws, size_t ws_size,
                              hipStream_t stream) {
    const float* x  = (const float*)d_in[0];
    const int* ei   = (const int*)d_in[1];
    const int* batch= (const int*)d_in[2];
    const float* W1 = (const float*)d_in[3];  const float* b1 = (const float*)d_in[4];
    const float* g1 = (const float*)d_in[5];  const float* be1= (const float*)d_in[6];
    const float* W2 = (const float*)d_in[7];  const float* b2 = (const float*)d_in[8];
    const float* g2 = (const float*)d_in[9];  const float* be2= (const float*)d_in[10];
    const float* W3 = (const float*)d_in[11]; const float* b3 = (const float*)d_in[12];
    const float* g3 = (const float*)d_in[13]; const float* be3= (const float*)d_in[14];
    const float* fcW= (const float*)d_in[15]; const float* fcb= (const float*)d_in[16];
    float* out = (float*)d_out;

    const int* row = ei;
    const int* col = ei + N_EDGES;

    // workspace layout
    char* wp = (char*)d_ws;
    float* dis        = (float*)wp;              wp += N_NODES * 4;
    int*   deg_i      = (int*)wp;                wp += N_NODES * 4;
    int*   row_ptr    = (int*)wp;                wp += N_NODES * 4;
    int*   bucket_cnt = (int*)wp;                wp += NBUCK * 4;
    int*   bucket_base= (int*)wp;                wp += NBUCK * 4;
    int*   bucket_cur = (int*)wp;                wp += NBUCK * 4;
    int*   sorted_row = (int*)wp;                wp += (size_t)N_EDGES * 4;
    unsigned* part_edges = (unsigned*)wp;        wp += (size_t)N_EDGES * 4;
    double* part_s    = (double*)wp;             wp += (size_t)NB_STATS * 64 * 8;
    double* part_q    = (double*)wp;             wp += (size_t)NB_STATS * 64 * 8;
    float* bn_mean    = (float*)wp;              wp += 64 * 4;
    float* bn_rstd    = (float*)wp;              wp += 64 * 4;
    float* pooled     = (float*)wp;              wp += 64 * 64 * 4;
    float* cnt        = (float*)wp;              wp += 64 * 4;
    _Float16* xs4h    = (_Float16*)wp;           wp += (size_t)N_NODES * 4 * 2;
    float* agg4       = (float*)wp;              wp += (size_t)N_NODES * 4 * 4;
    float* AGG        = (float*)wp;              wp += (size_t)N_NODES * 32 * 4;  // gather out (fp32)
    _Float16* PRE     = (_Float16*)wp;           wp += (size_t)N_NODES * 64 * 2;  // matmul out (fp16)
    _Float16* Hh      = (_Float16*)wp;           wp += (size_t)N_NODES * 32 * 2;  // h1/h2 (fp16, pre-scaled)
    _Float16* Hh3     = (_Float16*)wp;           wp += (size_t)N_NODES * 64 * 2;  // h3 (fp16) for pool

    const int BS = 256;

    // ---- CSR build: bucketed two-phase (no cross-XCD scatter)
    hipMemsetAsync(bucket_cnt, 0, NBUCK * sizeof(int), stream);
    part_hist_kernel<<<NB_PART, 256, 0, stream>>>(col, bucket_cnt);
    part_scan_kernel<<<1, NBUCK, 0, stream>>>(bucket_cnt, bucket_base, bucket_cur);
    part_scatter_kernel<<<NB_PART, 256, 0, stream>>>(row, col, bucket_cur, part_edges);
    csr_build_kernel<<<NBUCK, 256, 0, stream>>>(bucket_base, part_edges, row_ptr, deg_i, dis, sorted_row);

    // ---- layer 1: gather at F=4 (x padded, fp16), then 3->16 matmul
    scale_x_kernel<<<cdiv(N_NODES, BS), BS, 0, stream>>>(x, dis, xs4h);
    gather_kernel<4><<<cdiv((long long)cdiv(N_NODES, 32) * 64, BS), BS, 0, stream>>>(
        row_ptr, deg_i, sorted_row, dis, xs4h, agg4);
    matmul_stats_kernel<3, 16, 4><<<NB_STATS, 256, 0, stream>>>(agg4, W1, b1, PRE, part_s, part_q);
    bn_finalize_kernel<<<16, 256, 0, stream>>>(part_s, part_q, bn_mean, bn_rstd);
    bn_relu_kernel<16, true><<<cdiv((long long)N_NODES * 16, BS), BS, 0, stream>>>(
        PRE, bn_mean, bn_rstd, g1, be1, dis, Hh);  // Hh = h1 * dis (fp16)

    // ---- layer 2: gather at F=16 (f16x2), then 16->32 matmul
    gather_kernel<16><<<cdiv((long long)cdiv(N_NODES, 8) * 64, BS), BS, 0, stream>>>(
        row_ptr, deg_i, sorted_row, dis, Hh, AGG);
    matmul_stats_kernel<16, 32, 16><<<NB_STATS, 256, 0, stream>>>(AGG, W2, b2, PRE, part_s, part_q);
    bn_finalize_kernel<<<32, 256, 0, stream>>>(part_s, part_q, bn_mean, bn_rstd);
    bn_relu_kernel<32, true><<<cdiv((long long)N_NODES * 32, BS), BS, 0, stream>>>(
        PRE, bn_mean, bn_rstd, g2, be2, dis, Hh);  // Hh = h2 * dis (fp16)

    // ---- layer 3: gather at F=32 (f16x2), then 32->64 matmul
    gather_kernel<32><<<cdiv((long long)cdiv(N_NODES, 4) * 64, BS), BS, 0, stream>>>(
        row_ptr, deg_i, sorted_row, dis, Hh, AGG);
    matmul_stats_kernel<32, 64, 32><<<NB_STATS, 256, 0, stream>>>(AGG, W3, b3, PRE, part_s, part_q);
    bn_finalize_kernel<<<64, 256, 0, stream>>>(part_s, part_q, bn_mean, bn_rstd);
    bn_relu_kernel<64, false><<<cdiv((long long)N_NODES * 64, BS), BS, 0, stream>>>(
        PRE, bn_mean, bn_rstd, g3, be3, dis, Hh3);  // Hh3 = h3 (fp16)

    // ---- pool + fc
    hipMemsetAsync(pooled, 0, (64 * 64 + 64) * sizeof(float), stream);
    pool_kernel<<<cdiv((long long)cdiv(N_NODES, POOL_CHUNK) * 64, BS), BS, 0, stream>>>(Hh3, batch, pooled, cnt);
    final_kernel<<<1, B_GRAPHS * 10, 0, stream>>>(pooled, cnt, fcW, fcb, out);
}